// Round 4
// baseline (518.891 us; speedup 1.0000x reference)
//
#include <hip/hip_runtime.h>
#include <hip/hip_cooperative_groups.h>
#include <math.h>

#define N 1024
#define T 1024           // 16 waves: 4 per SIMD
#define HALF 512
#define PHASE_CAP 10
#define SWITCH 80        // in-block Boruvka only if comps > 80 (measured: never on this data)

typedef float v2f __attribute__((ext_vector_type(2)));
typedef unsigned long long ull;

#define INF64 0xFFFFFFFFFFFFFFFFull
#define INF32 0xFFFFFFFFu

__device__ __forceinline__ unsigned umin32(unsigned a, unsigned b) { return a < b ? a : b; }
__device__ __forceinline__ unsigned umax32(unsigned a, unsigned b) { return a > b ? a : b; }
__device__ __forceinline__ int imin32(int a, int b) { return a < b ? a : b; }

// Root walk with 2-cycle detection (keys globally distinct => cycles are exactly
// mutual pairs; root = min of the pair). Safe under concurrent parent[x] <- root(x).
__device__ __forceinline__ unsigned walk_root(const unsigned* parent, unsigned x) {
    unsigned prev = x, cur = parent[x];
    while (cur != prev) {
        unsigned nxt = parent[cur];
        if (nxt == prev) { cur = umin32(cur, prev); break; }
        prev = cur; cur = nxt;
    }
    return cur;
}

// DPP row_shr min step (row = 16 lanes), identity = 0xFFFFFFFF
#define DPP_MIN_SHR(v, sh)                                                                   \
    do {                                                                                     \
        unsigned _t = (unsigned)__builtin_amdgcn_update_dpp(                                 \
            (int)0xFFFFFFFF, (int)(v), 0x110 | (sh), 0xF, 0xF, false);                       \
        (v) = umin32((v), _t);                                                               \
    } while (0)

// ---------------- shared-memory layouts (union'd in the fused kernel) ----------------
struct ScanShared {                  // 48 KiB
    float px[N], py[N], pz[N];
    float stage[3 * N];
    unsigned cw[N];                  // comp label per node (scan2 only)
    unsigned parent[N];
    unsigned pb8[8][HALF];
};
struct FinalShared {                 // ~60.1 KiB
    float4 pts[N];                   // x, y, z, w = comp bits
    float4 spts[N];                  // staging scratch; later comp-sorted points (Prim)
    unsigned comp[N];
    ull bestComp[N];                 // merges: canonical best per root; Prim: segs (uint2)
    unsigned parent[N];
    unsigned pb[2][N];
    float deaths[N];
    unsigned wsum[16];               // counting-sort wave totals
    int deathCount;
};
union MegaShared {
    ScanShared s;
    FinalShared f;
};

// ---------------- phase-1 scan body: (cloud, node-half) per block ----------------
// 4 nodes x 128 j per thread; broadcast point-loads amortized over 4 relaxations.
__device__ __forceinline__ void scan1_body(ScanShared& S, const float* __restrict__ src,
                                           unsigned* __restrict__ bests1,
                                           int cloud, int nh, int t) {
    if (t < 768) ((float4*)S.stage)[t] = ((const float4*)src)[t];
    __syncthreads();
    S.px[t] = S.stage[3 * t]; S.py[t] = S.stage[3 * t + 1]; S.pz[t] = S.stage[3 * t + 2];
    __syncthreads();

    const int q = t & 127;           // node sub-id
    const int s = t >> 7;            // j-slice 0..7
    const int jbase = s << 7;
    const int n0 = nh * HALF + q;    // global node ids (4 per thread)
    const int n1 = n0 + 128, n2 = n0 + 256, n3 = n0 + 384;
    const v2f axA = (v2f){S.px[n0], S.px[n1]}, ayA = (v2f){S.py[n0], S.py[n1]},
              azA = (v2f){S.pz[n0], S.pz[n1]};
    const v2f axB = (v2f){S.px[n2], S.px[n3]}, ayB = (v2f){S.py[n2], S.py[n3]},
              azB = (v2f){S.pz[n2], S.pz[n3]};
    unsigned b0 = INF32, b1 = INF32, b2 = INF32, b3 = INF32;
    #pragma unroll 4
    for (int jj = 0; jj < 128; jj += 2) {
        const int j = jbase + jj;
        v2f qx = *(const v2f*)&S.px[j];    // ds_read_b64, wave-uniform -> broadcast
        v2f qy = *(const v2f*)&S.py[j];
        v2f qz = *(const v2f*)&S.pz[j];
        #define STEP1(SX, SY, SZ, JV)                                                   \
        {                                                                               \
            const v2f sxv = (v2f){SX, SX}, syv = (v2f){SY, SY}, szv = (v2f){SZ, SZ};    \
            v2f dxA = axA - sxv, dyA = ayA - syv, dzA = azA - szv;                      \
            v2f eA = dxA * dxA;                                                         \
            eA = __builtin_elementwise_fma(dyA, dyA, eA);                               \
            eA = __builtin_elementwise_fma(dzA, dzA, eA);                               \
            v2f dxB = axB - sxv, dyB = ayB - syv, dzB = azB - szv;                      \
            v2f eB = dxB * dxB;                                                         \
            eB = __builtin_elementwise_fma(dyB, dyB, eB);                               \
            eB = __builtin_elementwise_fma(dzB, dzB, eB);                               \
            unsigned kk;                                                                \
            kk = (__float_as_uint(eA.x) & 0xFFFFF800u) | (unsigned)(JV);                \
            b0 = umin32(b0, ((JV) == n0) ? INF32 : kk);                                 \
            kk = (__float_as_uint(eA.y) & 0xFFFFF800u) | (unsigned)(JV);                \
            b1 = umin32(b1, ((JV) == n1) ? INF32 : kk);                                 \
            kk = (__float_as_uint(eB.x) & 0xFFFFF800u) | (unsigned)(JV);                \
            b2 = umin32(b2, ((JV) == n2) ? INF32 : kk);                                 \
            kk = (__float_as_uint(eB.y) & 0xFFFFF800u) | (unsigned)(JV);                \
            b3 = umin32(b3, ((JV) == n3) ? INF32 : kk);                                 \
        }
        STEP1(qx.x, qy.x, qz.x, j)
        STEP1(qx.y, qy.y, qz.y, j + 1)
        #undef STEP1
    }
    S.pb8[s][q] = b0; S.pb8[s][q + 128] = b1; S.pb8[s][q + 256] = b2; S.pb8[s][q + 384] = b3;
    __syncthreads();
    if (t < HALF) {
        unsigned best = umin32(umin32(S.pb8[0][t], S.pb8[1][t]), umin32(S.pb8[2][t], S.pb8[3][t]));
        best = umin32(best, umin32(umin32(S.pb8[4][t], S.pb8[5][t]),
                                   umin32(S.pb8[6][t], S.pb8[7][t])));
        bests1[(size_t)cloud * N + nh * HALF + t] = best;
    }
}

// ---------------- phase-2 scan body: prologue rebuilds phase-1 comp labels ----------------
__device__ __forceinline__ void scan2_body(ScanShared& S, const float* __restrict__ src,
                                           const unsigned* __restrict__ bests1,
                                           unsigned* __restrict__ bests2,
                                           int cloud, int nh, int t) {
    if (t < 768) ((float4*)S.stage)[t] = ((const float4*)src)[t];
    __syncthreads();
    S.px[t] = S.stage[3 * t]; S.py[t] = S.stage[3 * t + 1]; S.pz[t] = S.stage[3 * t + 2];
    // merge-1 replay (labels only, no deaths): hook parent[t] = NN(t), min-rule walk
    S.parent[t] = bests1[(size_t)cloud * N + t] & 0x3FFu;
    __syncthreads();
    {
        unsigned r = walk_root(S.parent, (unsigned)t);
        S.parent[t] = r;
        S.cw[t] = r;
    }
    __syncthreads();

    const int q = t & 127;
    const int s = t >> 7;
    const int jbase = s << 7;
    const int n0 = nh * HALF + q;
    const int n1 = n0 + 128, n2 = n0 + 256, n3 = n0 + 384;
    const unsigned c0 = S.cw[n0], c1 = S.cw[n1], c2 = S.cw[n2], c3 = S.cw[n3];
    const v2f axA = (v2f){S.px[n0], S.px[n1]}, ayA = (v2f){S.py[n0], S.py[n1]},
              azA = (v2f){S.pz[n0], S.pz[n1]};
    const v2f axB = (v2f){S.px[n2], S.px[n3]}, ayB = (v2f){S.py[n2], S.py[n3]},
              azB = (v2f){S.pz[n2], S.pz[n3]};
    unsigned b0 = INF32, b1 = INF32, b2 = INF32, b3 = INF32;
    #pragma unroll 4
    for (int jj = 0; jj < 128; jj += 2) {
        const int j = jbase + jj;
        v2f qx = *(const v2f*)&S.px[j];
        v2f qy = *(const v2f*)&S.py[j];
        v2f qz = *(const v2f*)&S.pz[j];
        uint2 cj = *(const uint2*)&S.cw[j];
        #define STEP2(SX, SY, SZ, CJ, JV)                                               \
        {                                                                               \
            const v2f sxv = (v2f){SX, SX}, syv = (v2f){SY, SY}, szv = (v2f){SZ, SZ};    \
            v2f dxA = axA - sxv, dyA = ayA - syv, dzA = azA - szv;                      \
            v2f eA = dxA * dxA;                                                         \
            eA = __builtin_elementwise_fma(dyA, dyA, eA);                               \
            eA = __builtin_elementwise_fma(dzA, dzA, eA);                               \
            v2f dxB = axB - sxv, dyB = ayB - syv, dzB = azB - szv;                      \
            v2f eB = dxB * dxB;                                                         \
            eB = __builtin_elementwise_fma(dyB, dyB, eB);                               \
            eB = __builtin_elementwise_fma(dzB, dzB, eB);                               \
            unsigned kk;                                                                \
            kk = (__float_as_uint(eA.x) & 0xFFFFF800u) | (unsigned)(JV);                \
            b0 = umin32(b0, ((CJ) == c0) ? INF32 : kk);                                 \
            kk = (__float_as_uint(eA.y) & 0xFFFFF800u) | (unsigned)(JV);                \
            b1 = umin32(b1, ((CJ) == c1) ? INF32 : kk);                                 \
            kk = (__float_as_uint(eB.x) & 0xFFFFF800u) | (unsigned)(JV);                \
            b2 = umin32(b2, ((CJ) == c2) ? INF32 : kk);                                 \
            kk = (__float_as_uint(eB.y) & 0xFFFFF800u) | (unsigned)(JV);                \
            b3 = umin32(b3, ((CJ) == c3) ? INF32 : kk);                                 \
        }
        STEP2(qx.x, qy.x, qz.x, cj.x, j)
        STEP2(qx.y, qy.y, qz.y, cj.y, j + 1)
        #undef STEP2
    }
    S.pb8[s][q] = b0; S.pb8[s][q + 128] = b1; S.pb8[s][q + 256] = b2; S.pb8[s][q + 384] = b3;
    __syncthreads();
    if (t < HALF) {
        unsigned best = umin32(umin32(S.pb8[0][t], S.pb8[1][t]), umin32(S.pb8[2][t], S.pb8[3][t]));
        best = umin32(best, umin32(umin32(S.pb8[4][t], S.pb8[5][t]),
                                   umin32(S.pb8[6][t], S.pb8[7][t])));
        bests2[(size_t)cloud * N + nh * HALF + t] = best;
    }
}

// ---------------- final body: merges + (fallback phases) + contracted Prim + sort ----------------
__device__ void final_body(FinalShared& S, const float* __restrict__ src,
                           float* __restrict__ ws,
                           const unsigned* __restrict__ bests1,
                           const unsigned* __restrict__ bests2,
                           int nPre, int blk, int t) {
    // ---- stage + init ----
    {
        float* stg = (float*)&S.spts[0];
        if (t < 768) ((float4*)stg)[t] = ((const float4*)src)[t];
        __syncthreads();
        float x = stg[3 * t], y = stg[3 * t + 1], z = stg[3 * t + 2];
        S.pts[t] = make_float4(x, y, z, __uint_as_float((unsigned)t));
        S.comp[t] = (unsigned)t;
        S.parent[t] = (unsigned)t;
        S.deaths[t] = 0.0f;
        S.bestComp[t] = INF64;
    }
    if (t == 0) S.deathCount = 0;
    __syncthreads();

    const int n = t & (HALF - 1);
    const int h = t >> 9;
    const int n2 = n + HALF;
    const int jbase = h * HALF;
    float4 pA = S.pts[n], pB = S.pts[n2];
    const v2f pxv = (v2f){pA.x, pB.x};
    const v2f pyv = (v2f){pA.y, pB.y};
    const v2f pzv = (v2f){pA.z, pB.z};

    // ---- merge phase 1 from bests1 (every node is a root and hooks to its NN) ----
    if (nPre >= 1) {
        unsigned b1 = bests1[(size_t)blk * N + t];
        unsigned j1 = b1 & 0x3FFu;
        unsigned e1 = b1 & 0xFFFFF800u;
        S.parent[t] = j1;
        __syncthreads();
        {
            unsigned p = j1;
            unsigned gp = S.parent[p];
            bool mutual = (gp == (unsigned)t);
            bool rec = !mutual || ((unsigned)t < p);
            float dval = rec ? sqrtf(__uint_as_float(e1) + 1e-12f) : 0.0f;
            ull m = __ballot(rec);
            int cnt = __popcll(m);
            int base = 0;
            if ((t & 63) == 0 && cnt) base = atomicAdd(&S.deathCount, cnt);
            base = __shfl(base, 0, 64);
            if (rec) {
                int idx = base + __popcll(m & ((1ull << (t & 63)) - 1ull));
                if (idx < N - 1) S.deaths[idx] = dval;
            }
        }
        __syncthreads();
        {
            unsigned r = walk_root(S.parent, (unsigned)t);
            S.parent[t] = r;
            S.comp[t] = r;
            S.pts[t].w = __uint_as_float(r);
        }
        __syncthreads();
    }

    // ---- merge phase 2 from bests2 ----
    if (nPre >= 2) {
        unsigned b2 = bests2[(size_t)blk * N + t];
        if (b2 != INF32) {
            unsigned j2 = b2 & 0x3FFu, e2 = b2 & 0xFFFFF800u;
            unsigned mn = umin32((unsigned)t, j2), mx = umax32((unsigned)t, j2);
            atomicMin(&S.bestComp[S.comp[t]], ((ull)e2 << 20) | (ull)((mn << 10) | mx));
        }
        __syncthreads();
        const unsigned c = (unsigned)t;
        const bool isRoot = (S.parent[c] == c);
        {
            ull bc = S.bestComp[c];
            if (isRoot && bc != INF64) {
                unsigned mn = (unsigned)((bc >> 10) & 0x3FFu);
                unsigned mx = (unsigned)(bc & 0x3FFu);
                unsigned cm = S.comp[mn];
                S.parent[c] = (cm == c) ? S.comp[mx] : cm;
            }
        }
        __syncthreads();
        {
            bool rec = false;
            float dval = 0.0f;
            unsigned p = S.parent[c];
            if (isRoot && p != c) {
                unsigned gp = S.parent[p];
                bool mutual = (gp == c);
                rec = !mutual || (c < p);
                if (rec) dval = sqrtf(__uint_as_float((unsigned)(S.bestComp[c] >> 20)) + 1e-12f);
            }
            ull m = __ballot(rec);
            int cnt = __popcll(m);
            int base = 0;
            if ((t & 63) == 0 && cnt) base = atomicAdd(&S.deathCount, cnt);
            base = __shfl(base, 0, 64);
            if (rec) {
                int idx = base + __popcll(m & ((1ull << (t & 63)) - 1ull));
                if (idx < N - 1) S.deaths[idx] = dval;
            }
        }
        __syncthreads();
        {
            unsigned r = walk_root(S.parent, c);
            S.parent[t] = r;
            unsigned nc = walk_root(S.parent, S.comp[t]);
            S.comp[t] = nc;
            S.pts[t].w = __uint_as_float(nc);
            S.bestComp[t] = INF64;
        }
        __syncthreads();
    }

    // ---- in-kernel Boruvka phases (fallback path; never triggers with nPre=2 here) ----
    int phase = nPre;
    while (N - S.deathCount > SWITCH && phase < PHASE_CAP) {
        const unsigned c0 = S.comp[n], c1 = S.comp[n2];
        unsigned best0 = INF32, best1 = INF32;
        #pragma unroll 8
        for (int jj = 0; jj < HALF; ++jj) {
            int j = jbase + jj;
            float4 pj = S.pts[j];
            unsigned cj = __float_as_uint(pj.w);
            v2f dx = pxv - (v2f){pj.x, pj.x};
            v2f dy = pyv - (v2f){pj.y, pj.y};
            v2f dz = pzv - (v2f){pj.z, pj.z};
            v2f e = dx * dx;
            e = __builtin_elementwise_fma(dy, dy, e);
            e = __builtin_elementwise_fma(dz, dz, e);
            unsigned k0 = (__float_as_uint(e.x) & 0xFFFFF800u) | (unsigned)j;
            unsigned k1 = (__float_as_uint(e.y) & 0xFFFFF800u) | (unsigned)j;
            k0 = (cj == c0) ? INF32 : k0;
            k1 = (cj == c1) ? INF32 : k1;
            best0 = umin32(best0, k0);
            best1 = umin32(best1, k1);
        }
        S.pb[h][n] = best0;
        S.pb[h][n2] = best1;
        __syncthreads();
        if (h == 0) {
            #pragma unroll
            for (int s = 0; s < 2; ++s) {
                int m = s == 0 ? n : n2;
                unsigned fb = umin32(S.pb[0][m], S.pb[1][m]);
                if (fb != INF32) {
                    unsigned j = fb & 0x3FFu, e = fb & 0xFFFFF800u;
                    unsigned mn = umin32((unsigned)m, j), mx = umax32((unsigned)m, j);
                    ull key = ((ull)e << 20) | (ull)((mn << 10) | mx);
                    if (phase == 0) S.bestComp[m] = key;
                    else atomicMin(&S.bestComp[S.comp[m]], key);
                }
            }
        }
        __syncthreads();
        const unsigned c = (unsigned)t;
        const bool isRoot = (S.parent[c] == c);
        {
            ull bc = S.bestComp[c];
            if (isRoot && bc != INF64) {
                unsigned mn = (unsigned)((bc >> 10) & 0x3FFu);
                unsigned mx = (unsigned)(bc & 0x3FFu);
                unsigned cm = S.comp[mn];
                S.parent[c] = (cm == c) ? S.comp[mx] : cm;
            }
        }
        __syncthreads();
        {
            bool rec = false;
            float dval = 0.0f;
            unsigned p = S.parent[c];
            if (isRoot && p != c) {
                unsigned gp = S.parent[p];
                bool mutual = (gp == c);
                rec = !mutual || (c < p);
                if (rec) dval = sqrtf(__uint_as_float((unsigned)(S.bestComp[c] >> 20)) + 1e-12f);
            }
            ull m = __ballot(rec);
            int cnt = __popcll(m);
            int base = 0;
            if ((t & 63) == 0 && cnt) base = atomicAdd(&S.deathCount, cnt);
            base = __shfl(base, 0, 64);
            if (rec) {
                int idx = base + __popcll(m & ((1ull << (t & 63)) - 1ull));
                if (idx < N - 1) S.deaths[idx] = dval;
            }
        }
        __syncthreads();
        {
            unsigned r = walk_root(S.parent, c);
            S.parent[t] = r;
            unsigned nc = walk_root(S.parent, S.comp[t]);
            S.comp[t] = nc;
            S.pts[t].w = __uint_as_float(nc);
            S.bestComp[t] = INF64;
        }
        __syncthreads();
        ++phase;
    }

    // ================= Contracted Prim on remaining comps =================
    const int dcbase = S.deathCount;
    const int comps = N - dcbase;
    if (comps > 1) {
        unsigned* scomp = &S.pb[0][0];     // comp id per sorted slot
        unsigned* hist = &S.pb[1][0];      // counts -> running offsets (dead after scatter)
        unsigned* wavemin = &S.pb[1][0];   // double-buffered: [ (step&1)*8 + wid ]
        uint2* segs = (uint2*)&S.bestComp[0];
        const int lane = t & 63;
        const int wid = t >> 6;

        hist[t] = 0;
        __syncthreads();
        atomicAdd(&hist[S.comp[t]], 1u);
        __syncthreads();
        unsigned cnt = hist[t];
        unsigned inc = cnt;
        #pragma unroll
        for (int d = 1; d < 64; d <<= 1) {           // intra-wave inclusive scan
            unsigned u = __shfl_up(inc, d, 64);
            if (lane >= d) inc += u;
        }
        if (lane == 63) S.wsum[wid] = inc;
        __syncthreads();
        unsigned wof = 0;
        for (int i = 0; i < wid; ++i) wof += S.wsum[i];   // broadcast reads, <=15
        unsigned excl = wof + inc - cnt;                // exclusive start of bin t
        if (cnt) { segs[t].x = excl; segs[t].y = excl + cnt; }
        __syncthreads();
        hist[t] = excl;                  // running scatter cursor per bin
        __syncthreads();
        {
            unsigned pos = atomicAdd(&hist[S.comp[t]], 1u);
            S.spts[pos] = S.pts[t];
            scomp[pos] = S.comp[t];
        }
        __syncthreads();

        unsigned c_cur = S.comp[0];
        v2f pxv2 = (v2f){0.f, 0.f}, pyv2 = pxv2, pzv2 = pxv2;
        unsigned myc0 = 0, myc1 = 0, md0 = INF32, md1 = INF32;
        if (t < HALF) {
            float4 q0 = S.spts[t], q1 = S.spts[t + HALF];
            myc0 = scomp[t];
            myc1 = scomp[t + HALF];
            pxv2 = (v2f){q0.x, q1.x};
            pyv2 = (v2f){q0.y, q1.y};
            pzv2 = (v2f){q0.z, q1.z};
            if (myc0 == c_cur) pxv2.x = INFINITY;   // in-tree poison
            if (myc1 == c_cur) pxv2.y = INFINITY;
        }

        for (int step = 0; step < comps - 1; ++step) {
            if (t < HALF) {
                uint2 sg = segs[c_cur];          // ds_read_b64, uniform -> broadcast
                const int jb = (int)sg.x, je = (int)sg.y, jl = je - 1;
                for (int base = jb; base < je; base += 4) {
                    float4 q0 = S.spts[base];
                    float4 q1 = S.spts[imin32(base + 1, jl)];
                    float4 q2 = S.spts[imin32(base + 2, jl)];
                    float4 q3 = S.spts[imin32(base + 3, jl)];
                    #define RELAX(qq)                                                        \
                        {                                                                    \
                            v2f dx = pxv2 - (v2f){qq.x, qq.x};                               \
                            v2f dy = pyv2 - (v2f){qq.y, qq.y};                               \
                            v2f dz = pzv2 - (v2f){qq.z, qq.z};                               \
                            v2f e = dx * dx;                                                 \
                            e = __builtin_elementwise_fma(dy, dy, e);                        \
                            e = __builtin_elementwise_fma(dz, dz, e);                        \
                            md0 = umin32(md0, (__float_as_uint(e.x) & 0xFFFFFC00u) | myc0);  \
                            md1 = umin32(md1, (__float_as_uint(e.y) & 0xFFFFFC00u) | myc1);  \
                        }
                    RELAX(q0) RELAX(q1) RELAX(q2) RELAX(q3)
                    #undef RELAX
                }
                unsigned v = umin32(md0, md1);
                DPP_MIN_SHR(v, 1);
                DPP_MIN_SHR(v, 2);
                DPP_MIN_SHR(v, 4);
                DPP_MIN_SHR(v, 8);
                unsigned r0 = (unsigned)__builtin_amdgcn_readlane((int)v, 15);
                unsigned r1 = (unsigned)__builtin_amdgcn_readlane((int)v, 31);
                unsigned r2 = (unsigned)__builtin_amdgcn_readlane((int)v, 47);
                unsigned r3 = (unsigned)__builtin_amdgcn_readlane((int)v, 63);
                if (lane == 0)
                    wavemin[(step & 1) * 8 + wid] = umin32(umin32(r0, r1), umin32(r2, r3));
            }
            __syncthreads();                     // single barrier per step (dbuf-safe)
            if (t < HALF) {
                const uint4* wmv = (const uint4*)(wavemin + (step & 1) * 8);
                uint4 u0 = wmv[0], u1 = wmv[1];
                unsigned m0 = umin32(umin32(u0.x, u0.y), umin32(u0.z, u0.w));
                unsigned m1 = umin32(umin32(u1.x, u1.y), umin32(u1.z, u1.w));
                unsigned G = umin32(m0, m1);
                c_cur = G & 0x3FFu;              // comp id directly
                if (t == 0)
                    S.deaths[dcbase + step] = sqrtf(__uint_as_float(G & 0xFFFFFC00u) + 1e-12f);
                if (myc0 == c_cur) { pxv2.x = INFINITY; md0 = INF32; }
                if (myc1 == c_cur) { pxv2.y = INFINITY; md1 = INF32; }
            }
        }
    }

    // ---- hybrid bitonic sort of 1024 floats (1023 deaths + INF pad) ascending ----
    if (t == 0) S.deaths[N - 1] = INFINITY;
    __syncthreads();
    {
        float v = S.deaths[t];
        #pragma unroll
        for (int k = 2; k <= N; k <<= 1) {
            const bool up = ((t & k) == 0);
            #pragma unroll
            for (int j = k >> 1; j > 0; j >>= 1) {
                float u;
                if (j >= 64) {
                    S.deaths[t] = v;
                    __syncthreads();
                    u = S.deaths[t ^ j];
                    __syncthreads();
                } else {
                    u = __shfl_xor(v, j, 64);
                }
                v = (((t & j) == 0) == up) ? fminf(v, u) : fmaxf(v, u);
            }
        }
        float* dst = ws + (size_t)blk * N;
        dst[t] = (t < N - 1) ? v : 0.0f;
    }
}

// ---------------- fused cooperative kernel: scan1 | sync | scan2 | sync | final ----------------
__global__ __launch_bounds__(T) void mega_kernel(const float* __restrict__ gts,
                                                 const float* __restrict__ preds,
                                                 float* __restrict__ ws,
                                                 unsigned* __restrict__ bests1,
                                                 unsigned* __restrict__ bests2) {
    __shared__ MegaShared u;
    const int t = threadIdx.x;
    const int b = blockIdx.x;

    {   // scan1 role: (cloud, half) = (b>>1, b&1)
        const int cloud = b >> 1, nh = b & 1;
        const float* src = (cloud < 64 ? gts : preds) + (size_t)(cloud & 63) * N * 3;
        scan1_body(u.s, src, bests1, cloud, nh, t);
    }
    __threadfence();                               // device-scope release of bests1
    cooperative_groups::this_grid().sync();
    __threadfence();                               // acquire (per-XCD L2 non-coherence)
    {   // scan2 role
        const int cloud = b >> 1, nh = b & 1;
        const float* src = (cloud < 64 ? gts : preds) + (size_t)(cloud & 63) * N * 3;
        scan2_body(u.s, src, bests1, bests2, cloud, nh, t);
    }
    __threadfence();
    cooperative_groups::this_grid().sync();
    __threadfence();
    if (b >= 128) return;                          // no further grid syncs: early exit is legal
    const float* src = (b < 64 ? gts : preds) + (size_t)(b & 63) * N * 3;
    final_body(u.f, src, ws, bests1, bests2, 2, b, t);
}

// ---------------- standalone wrappers (host-side fallback if coop launch fails) ----------------
__global__ __launch_bounds__(T) void scan1_kernel(const float* __restrict__ gts,
                                                  const float* __restrict__ preds,
                                                  unsigned* __restrict__ bests1) {
    __shared__ ScanShared S;
    const int cloud = blockIdx.x >> 1, nh = blockIdx.x & 1;
    const float* src = (cloud < 64 ? gts : preds) + (size_t)(cloud & 63) * N * 3;
    scan1_body(S, src, bests1, cloud, nh, threadIdx.x);
}
__global__ __launch_bounds__(T) void scan2_kernel(const float* __restrict__ gts,
                                                  const float* __restrict__ preds,
                                                  const unsigned* __restrict__ bests1,
                                                  unsigned* __restrict__ bests2) {
    __shared__ ScanShared S;
    const int cloud = blockIdx.x >> 1, nh = blockIdx.x & 1;
    const float* src = (cloud < 64 ? gts : preds) + (size_t)(cloud & 63) * N * 3;
    scan2_body(S, src, bests1, bests2, cloud, nh, threadIdx.x);
}
__global__ __launch_bounds__(T) void final_kernel(const float* __restrict__ gts,
                                                  const float* __restrict__ preds,
                                                  float* __restrict__ ws,
                                                  const unsigned* __restrict__ bests1,
                                                  const unsigned* __restrict__ bests2,
                                                  int nPre) {
    __shared__ FinalShared S;
    const int blk = blockIdx.x;
    const float* src = (blk < 64 ? gts : preds) + (size_t)(blk & 63) * N * 3;
    final_body(S, src, ws, bests1, bests2, nPre, blk, threadIdx.x);
}

// Fused diff: 64 blocks; per-batch |a-b| sum -> atomicAdd into out (pre-zeroed).
__global__ __launch_bounds__(256) void diff_kernel(const float* __restrict__ ws,
                                                   float* __restrict__ out) {
    __shared__ float red[4];
    const int t = threadIdx.x;
    const int b = blockIdx.x;
    const float* a = ws + (size_t)b * N;
    const float* c = ws + (size_t)(64 + b) * N;
    float sum = 0.0f;
    for (int i = t; i < N; i += 256)
        sum += fabsf(a[i] - c[i]);
    #pragma unroll
    for (int off = 32; off > 0; off >>= 1)
        sum += __shfl_down(sum, off, 64);
    if ((t & 63) == 0) red[t >> 6] = sum;
    __syncthreads();
    if (t == 0)
        atomicAdd(out, (red[0] + red[1] + red[2] + red[3]) * (1.0f / 64.0f));
}

extern "C" void kernel_launch(void* const* d_in, const int* in_sizes, int n_in,
                              void* d_out, int out_size, void* d_ws, size_t ws_size,
                              hipStream_t stream) {
    const float* gts = (const float*)d_in[0];
    const float* preds = (const float*)d_in[1];
    float* ws = (float*)d_ws;                     // sorted deaths live at ws[0 .. 128*N)
    unsigned* bests1 = (unsigned*)d_ws;           // 512 KiB (overwritten by sorted deaths)
    unsigned* bests2 = bests1 + 128 * N;          // 512 KiB
    const bool big = ws_size >= (size_t)(2u * 128u * N * 4u);

    if (big) {
        void* args[5];
        args[0] = (void*)&gts;
        args[1] = (void*)&preds;
        args[2] = (void*)&ws;
        args[3] = (void*)&bests1;
        args[4] = (void*)&bests2;
        hipError_t cerr = hipLaunchCooperativeKernel((const void*)mega_kernel,
                                                     dim3(256), dim3(T), args, 0, stream);
        if (cerr != hipSuccess) {
            // clean fallback: original 3-kernel sequence
            hipLaunchKernelGGL(scan1_kernel, dim3(256), dim3(T), 0, stream, gts, preds, bests1);
            hipLaunchKernelGGL(scan2_kernel, dim3(256), dim3(T), 0, stream,
                               gts, preds, bests1, bests2);
            hipLaunchKernelGGL(final_kernel, dim3(128), dim3(T), 0, stream,
                               gts, preds, ws, bests1, bests2, 2);
        }
    } else {
        hipLaunchKernelGGL(final_kernel, dim3(128), dim3(T), 0, stream,
                           gts, preds, ws, (const unsigned*)nullptr, (const unsigned*)nullptr, 0);
    }
    hipMemsetAsync(d_out, 0, sizeof(float), stream);   // out accumulated via atomicAdd
    hipLaunchKernelGGL(diff_kernel, dim3(64), dim3(256), 0, stream, ws, (float*)d_out);
}

// Round 5
// 323.943 us; speedup vs baseline: 1.6018x; 1.6018x over previous
//
#include <hip/hip_runtime.h>
#include <math.h>

#define N 1024
#define T 1024           // 16 waves: 4 per SIMD
#define HALF 512
#define PHASE_CAP 10
#define SWITCH 80        // in-block Boruvka only if comps > 80 (measured: never on this data)

typedef float v2f __attribute__((ext_vector_type(2)));
typedef unsigned long long ull;

#define INF64 0xFFFFFFFFFFFFFFFFull
#define INF32 0xFFFFFFFFu

__device__ __forceinline__ unsigned umin32(unsigned a, unsigned b) { return a < b ? a : b; }
__device__ __forceinline__ unsigned umax32(unsigned a, unsigned b) { return a > b ? a : b; }
__device__ __forceinline__ int imin32(int a, int b) { return a < b ? a : b; }

// Root walk with 2-cycle detection (keys globally distinct => cycles are exactly
// mutual pairs; root = min of the pair). Safe under concurrent parent[x] <- root(x).
__device__ __forceinline__ unsigned walk_root(const unsigned* parent, unsigned x) {
    unsigned prev = x, cur = parent[x];
    while (cur != prev) {
        unsigned nxt = parent[cur];
        if (nxt == prev) { cur = umin32(cur, prev); break; }
        prev = cur; cur = nxt;
    }
    return cur;
}

// DPP row_shr min step (row = 16 lanes), identity = 0xFFFFFFFF
#define DPP_MIN_SHR(v, sh)                                                                   \
    do {                                                                                     \
        unsigned _t = (unsigned)__builtin_amdgcn_update_dpp(                                 \
            (int)0xFFFFFFFF, (int)(v), 0x110 | (sh), 0xF, 0xF, false);                       \
        (v) = umin32((v), _t);                                                               \
    } while (0)

// ======================= fused one-block-per-cloud kernel =======================
// Everything block-local: scan1 -> merge1 -> scan2 -> merge2 -> (Boruvka) -> Prim
// -> sort -> dst; last-arriving block computes the diff. No grid sync, no global
// intermediates (round-4 lesson: grid.sync + device fences cost ~330 us).
struct MegaSmem {
    float4 pts[N];               // 16K: x,y,z,w=comp bits (stable all phases)
    float deaths[N];             // 4K  (stable)
    ull bestComp[N];             // 8K: merge canonical best; Prim segs (uint2)
    unsigned comp[N];            // 4K  (stable)
    unsigned pb[2][N];           // 8K: scan rows 0-1; Boruvka pb; Prim scomp/hist/wavemin
    union {                      // 16K overlay
        struct {
            unsigned pb4hi[2][N];   // scan rows 2-3
            unsigned bests[N];      // scan output / merge input
            unsigned parent[N];     // union-find (dead before Prim)
        } a;
        float4 spts[N];          // Prim comp-sorted points
        float stage[3 * N];      // prologue staging
    } u;
    unsigned wsum[16];
    int deathCount;
    int ticket;
    float red4[2][4][4];         // last-block diff cells (double-buffered)
};

// 4 nodes x 256 j per thread; q=t&255 owns nodes {q,q+256,q+512,q+768},
// s=t>>8 scans j-slice [s*256,(s+1)*256). Broadcast b128 point loads amortized 4x.
template <bool SUPP_COMP>
__device__ __forceinline__ void scan_pass(MegaSmem& S, int t) {
    const int q = t & 255;
    const int s = t >> 8;
    const int jbase = s << 8;
    const int n0 = q, n1 = q + 256, n2 = q + 512, n3 = q + 768;
    const float4 p0 = S.pts[n0], p1 = S.pts[n1], p2 = S.pts[n2], p3 = S.pts[n3];
    const v2f axA = (v2f){p0.x, p1.x}, ayA = (v2f){p0.y, p1.y}, azA = (v2f){p0.z, p1.z};
    const v2f axB = (v2f){p2.x, p3.x}, ayB = (v2f){p2.y, p3.y}, azB = (v2f){p2.z, p3.z};
    unsigned c0 = 0, c1 = 0, c2 = 0, c3 = 0;
    if (SUPP_COMP) { c0 = S.comp[n0]; c1 = S.comp[n1]; c2 = S.comp[n2]; c3 = S.comp[n3]; }
    unsigned b0 = INF32, b1 = INF32, b2 = INF32, b3 = INF32;
    #pragma unroll 4
    for (int jj = 0; jj < 256; jj += 2) {
        const int j = jbase + jj;
        const float4 qa = S.pts[j];          // ds_read_b128, wave-uniform broadcast
        const float4 qb = S.pts[j + 1];
        uint2 cj;
        if (SUPP_COMP) cj = *(const uint2*)&S.comp[j];
        #define MSTEP(QQ, CJV, JV)                                                       \
        {                                                                                \
            const v2f sxv = (v2f){QQ.x, QQ.x}, syv = (v2f){QQ.y, QQ.y},                  \
                      szv = (v2f){QQ.z, QQ.z};                                           \
            v2f dxA = axA - sxv, dyA = ayA - syv, dzA = azA - szv;                       \
            v2f eA = dxA * dxA;                                                          \
            eA = __builtin_elementwise_fma(dyA, dyA, eA);                                \
            eA = __builtin_elementwise_fma(dzA, dzA, eA);                                \
            v2f dxB = axB - sxv, dyB = ayB - syv, dzB = azB - szv;                       \
            v2f eB = dxB * dxB;                                                          \
            eB = __builtin_elementwise_fma(dyB, dyB, eB);                                \
            eB = __builtin_elementwise_fma(dzB, dzB, eB);                                \
            unsigned kk;                                                                 \
            kk = (__float_as_uint(eA.x) & 0xFFFFF800u) | (unsigned)(JV);                 \
            b0 = umin32(b0, (SUPP_COMP ? ((CJV) == c0) : ((JV) == n0)) ? INF32 : kk);    \
            kk = (__float_as_uint(eA.y) & 0xFFFFF800u) | (unsigned)(JV);                 \
            b1 = umin32(b1, (SUPP_COMP ? ((CJV) == c1) : ((JV) == n1)) ? INF32 : kk);    \
            kk = (__float_as_uint(eB.x) & 0xFFFFF800u) | (unsigned)(JV);                 \
            b2 = umin32(b2, (SUPP_COMP ? ((CJV) == c2) : ((JV) == n2)) ? INF32 : kk);    \
            kk = (__float_as_uint(eB.y) & 0xFFFFF800u) | (unsigned)(JV);                 \
            b3 = umin32(b3, (SUPP_COMP ? ((CJV) == c3) : ((JV) == n3)) ? INF32 : kk);    \
        }
        MSTEP(qa, cj.x, j)
        MSTEP(qb, cj.y, j + 1)
        #undef MSTEP
    }
    unsigned* prow = (s < 2) ? &S.pb[s][0] : &S.u.a.pb4hi[s - 2][0];
    prow[n0] = b0; prow[n1] = b1; prow[n2] = b2; prow[n3] = b3;
    __syncthreads();
    {
        unsigned best = umin32(umin32(S.pb[0][t], S.pb[1][t]),
                               umin32(S.u.a.pb4hi[0][t], S.u.a.pb4hi[1][t]));
        S.u.a.bests[t] = best;
    }
    __syncthreads();
}

__global__ __launch_bounds__(T) void mega_kernel(const float* __restrict__ gts,
                                                 const float* __restrict__ preds,
                                                 float* __restrict__ ws,
                                                 float* __restrict__ out,
                                                 unsigned* __restrict__ ctr) {
    __shared__ MegaSmem S;
    const int t = threadIdx.x;
    const int blk = blockIdx.x;
    const float* __restrict__ src = (blk < 64 ? gts : preds) + (size_t)(blk & 63) * N * 3;

    // ---- stage + init (stage overlays parent: register-hold across barrier) ----
    if (t < 768) ((float4*)S.u.stage)[t] = ((const float4*)src)[t];
    __syncthreads();
    {
        const float x = S.u.stage[3 * t], y = S.u.stage[3 * t + 1], z = S.u.stage[3 * t + 2];
        __syncthreads();                 // stage dead before parent (aliased) is written
        S.pts[t] = make_float4(x, y, z, __uint_as_float((unsigned)t));
        S.comp[t] = (unsigned)t;
        S.u.a.parent[t] = (unsigned)t;
        S.deaths[t] = 0.0f;
        S.bestComp[t] = INF64;
        if (t == 0) S.deathCount = 0;
    }
    __syncthreads();

    // ---- scan1 (self-suppress by index) ----
    scan_pass<false>(S, t);

    // ---- merge1 from bests (every node roots and hooks to its NN) ----
    {
        unsigned b1v = S.u.a.bests[t];
        unsigned j1 = b1v & 0x3FFu;
        unsigned e1 = b1v & 0xFFFFF800u;
        S.u.a.parent[t] = j1;
        __syncthreads();
        {
            unsigned p = j1;
            unsigned gp = S.u.a.parent[p];
            bool mutual = (gp == (unsigned)t);
            bool rec = !mutual || ((unsigned)t < p);
            float dval = rec ? sqrtf(__uint_as_float(e1) + 1e-12f) : 0.0f;
            ull m = __ballot(rec);
            int cnt = __popcll(m);
            int base = 0;
            if ((t & 63) == 0 && cnt) base = atomicAdd(&S.deathCount, cnt);
            base = __shfl(base, 0, 64);
            if (rec) {
                int idx = base + __popcll(m & ((1ull << (t & 63)) - 1ull));
                if (idx < N - 1) S.deaths[idx] = dval;
            }
        }
        __syncthreads();
        {
            unsigned r = walk_root(S.u.a.parent, (unsigned)t);
            S.u.a.parent[t] = r;
            S.comp[t] = r;
            S.pts[t].w = __uint_as_float(r);
        }
        __syncthreads();
    }

    // ---- scan2 (suppress same-component; labels = merge1's, identical to old replay) ----
    scan_pass<true>(S, t);

    // ---- merge2 ----
    {
        unsigned b2v = S.u.a.bests[t];
        if (b2v != INF32) {
            unsigned j2 = b2v & 0x3FFu, e2 = b2v & 0xFFFFF800u;
            unsigned mn = umin32((unsigned)t, j2), mx = umax32((unsigned)t, j2);
            atomicMin(&S.bestComp[S.comp[t]], ((ull)e2 << 20) | (ull)((mn << 10) | mx));
        }
        __syncthreads();
        const unsigned c = (unsigned)t;
        const bool isRoot = (S.u.a.parent[c] == c);
        {
            ull bc = S.bestComp[c];
            if (isRoot && bc != INF64) {
                unsigned mn = (unsigned)((bc >> 10) & 0x3FFu);
                unsigned mx = (unsigned)(bc & 0x3FFu);
                unsigned cm = S.comp[mn];
                S.u.a.parent[c] = (cm == c) ? S.comp[mx] : cm;
            }
        }
        __syncthreads();
        {
            bool rec = false;
            float dval = 0.0f;
            unsigned p = S.u.a.parent[c];
            if (isRoot && p != c) {
                unsigned gp = S.u.a.parent[p];
                bool mutual = (gp == c);
                rec = !mutual || (c < p);
                if (rec) dval = sqrtf(__uint_as_float((unsigned)(S.bestComp[c] >> 20)) + 1e-12f);
            }
            ull m = __ballot(rec);
            int cnt = __popcll(m);
            int base = 0;
            if ((t & 63) == 0 && cnt) base = atomicAdd(&S.deathCount, cnt);
            base = __shfl(base, 0, 64);
            if (rec) {
                int idx = base + __popcll(m & ((1ull << (t & 63)) - 1ull));
                if (idx < N - 1) S.deaths[idx] = dval;
            }
        }
        __syncthreads();
        {
            unsigned r = walk_root(S.u.a.parent, c);
            S.u.a.parent[t] = r;
            unsigned nc = walk_root(S.u.a.parent, S.comp[t]);
            S.comp[t] = nc;
            S.pts[t].w = __uint_as_float(nc);
            S.bestComp[t] = INF64;
        }
        __syncthreads();
    }

    // ---- in-block Boruvka phases (fallback; never triggers on this data) ----
    {
        const int n = t & (HALF - 1);
        const int h = t >> 9;
        const int n2 = n + HALF;
        const int jb2 = h * HALF;
        float4 pA = S.pts[n], pB = S.pts[n2];
        const v2f pxv = (v2f){pA.x, pB.x};
        const v2f pyv = (v2f){pA.y, pB.y};
        const v2f pzv = (v2f){pA.z, pB.z};
        int phase = 2;
        while (N - S.deathCount > SWITCH && phase < PHASE_CAP) {
            const unsigned c0 = S.comp[n], c1 = S.comp[n2];
            unsigned best0 = INF32, best1 = INF32;
            #pragma unroll 8
            for (int jj = 0; jj < HALF; ++jj) {
                int j = jb2 + jj;
                float4 pj = S.pts[j];
                unsigned cj = __float_as_uint(pj.w);
                v2f dx = pxv - (v2f){pj.x, pj.x};
                v2f dy = pyv - (v2f){pj.y, pj.y};
                v2f dz = pzv - (v2f){pj.z, pj.z};
                v2f e = dx * dx;
                e = __builtin_elementwise_fma(dy, dy, e);
                e = __builtin_elementwise_fma(dz, dz, e);
                unsigned k0 = (__float_as_uint(e.x) & 0xFFFFF800u) | (unsigned)j;
                unsigned k1 = (__float_as_uint(e.y) & 0xFFFFF800u) | (unsigned)j;
                k0 = (cj == c0) ? INF32 : k0;
                k1 = (cj == c1) ? INF32 : k1;
                best0 = umin32(best0, k0);
                best1 = umin32(best1, k1);
            }
            S.pb[h][n] = best0;
            S.pb[h][n2] = best1;
            __syncthreads();
            if (h == 0) {
                #pragma unroll
                for (int sS = 0; sS < 2; ++sS) {
                    int m = sS == 0 ? n : n2;
                    unsigned fb = umin32(S.pb[0][m], S.pb[1][m]);
                    if (fb != INF32) {
                        unsigned j = fb & 0x3FFu, e = fb & 0xFFFFF800u;
                        unsigned mn = umin32((unsigned)m, j), mx = umax32((unsigned)m, j);
                        ull key = ((ull)e << 20) | (ull)((mn << 10) | mx);
                        atomicMin(&S.bestComp[S.comp[m]], key);
                    }
                }
            }
            __syncthreads();
            const unsigned c = (unsigned)t;
            const bool isRoot = (S.u.a.parent[c] == c);
            {
                ull bc = S.bestComp[c];
                if (isRoot && bc != INF64) {
                    unsigned mn = (unsigned)((bc >> 10) & 0x3FFu);
                    unsigned mx = (unsigned)(bc & 0x3FFu);
                    unsigned cm = S.comp[mn];
                    S.u.a.parent[c] = (cm == c) ? S.comp[mx] : cm;
                }
            }
            __syncthreads();
            {
                bool rec = false;
                float dval = 0.0f;
                unsigned p = S.u.a.parent[c];
                if (isRoot && p != c) {
                    unsigned gp = S.u.a.parent[p];
                    bool mutual = (gp == c);
                    rec = !mutual || (c < p);
                    if (rec)
                        dval = sqrtf(__uint_as_float((unsigned)(S.bestComp[c] >> 20)) + 1e-12f);
                }
                ull m = __ballot(rec);
                int cnt = __popcll(m);
                int base = 0;
                if ((t & 63) == 0 && cnt) base = atomicAdd(&S.deathCount, cnt);
                base = __shfl(base, 0, 64);
                if (rec) {
                    int idx = base + __popcll(m & ((1ull << (t & 63)) - 1ull));
                    if (idx < N - 1) S.deaths[idx] = dval;
                }
            }
            __syncthreads();
            {
                unsigned r = walk_root(S.u.a.parent, c);
                S.u.a.parent[t] = r;
                unsigned nc = walk_root(S.u.a.parent, S.comp[t]);
                S.comp[t] = nc;
                S.pts[t].w = __uint_as_float(nc);
                S.bestComp[t] = INF64;
            }
            __syncthreads();
            ++phase;
        }
    }

    // ================= Contracted Prim on remaining comps =================
    const int dcbase = S.deathCount;
    const int comps = N - dcbase;
    if (comps > 1) {
        unsigned* scomp = &S.pb[0][0];     // comp id per sorted slot
        unsigned* hist = &S.pb[1][0];      // counts -> running offsets
        unsigned* wavemin = &S.pb[1][0];   // double-buffered: [(step&1)*8 + wid]
        uint2* segs = (uint2*)&S.bestComp[0];
        const int lane = t & 63;
        const int wid = t >> 6;

        hist[t] = 0;
        __syncthreads();
        atomicAdd(&hist[S.comp[t]], 1u);
        __syncthreads();
        unsigned cnt = hist[t];
        unsigned inc = cnt;
        #pragma unroll
        for (int d = 1; d < 64; d <<= 1) {
            unsigned uu = __shfl_up(inc, d, 64);
            if (lane >= d) inc += uu;
        }
        if (lane == 63) S.wsum[wid] = inc;
        __syncthreads();
        unsigned wof = 0;
        for (int i = 0; i < wid; ++i) wof += S.wsum[i];
        unsigned excl = wof + inc - cnt;
        if (cnt) { segs[t].x = excl; segs[t].y = excl + cnt; }
        __syncthreads();
        hist[t] = excl;
        __syncthreads();
        {
            unsigned pos = atomicAdd(&hist[S.comp[t]], 1u);
            S.u.spts[pos] = S.pts[t];       // parent/bests/pb4hi dead: overlay is free
            scomp[pos] = S.comp[t];
        }
        __syncthreads();

        unsigned c_cur = S.comp[0];
        v2f pxv2 = (v2f){0.f, 0.f}, pyv2 = pxv2, pzv2 = pxv2;
        unsigned myc0 = 0, myc1 = 0, md0 = INF32, md1 = INF32;
        if (t < HALF) {
            float4 q0 = S.u.spts[t], q1 = S.u.spts[t + HALF];
            myc0 = scomp[t];
            myc1 = scomp[t + HALF];
            pxv2 = (v2f){q0.x, q1.x};
            pyv2 = (v2f){q0.y, q1.y};
            pzv2 = (v2f){q0.z, q1.z};
            if (myc0 == c_cur) pxv2.x = INFINITY;
            if (myc1 == c_cur) pxv2.y = INFINITY;
        }

        for (int step = 0; step < comps - 1; ++step) {
            if (t < HALF) {
                uint2 sg = segs[c_cur];
                const int jb = (int)sg.x, je = (int)sg.y, jl = je - 1;
                for (int base = jb; base < je; base += 4) {
                    float4 q0 = S.u.spts[base];
                    float4 q1 = S.u.spts[imin32(base + 1, jl)];
                    float4 q2 = S.u.spts[imin32(base + 2, jl)];
                    float4 q3 = S.u.spts[imin32(base + 3, jl)];
                    #define RELAX(qq)                                                        \
                        {                                                                    \
                            v2f dx = pxv2 - (v2f){qq.x, qq.x};                               \
                            v2f dy = pyv2 - (v2f){qq.y, qq.y};                               \
                            v2f dz = pzv2 - (v2f){qq.z, qq.z};                               \
                            v2f e = dx * dx;                                                 \
                            e = __builtin_elementwise_fma(dy, dy, e);                        \
                            e = __builtin_elementwise_fma(dz, dz, e);                        \
                            md0 = umin32(md0, (__float_as_uint(e.x) & 0xFFFFFC00u) | myc0);  \
                            md1 = umin32(md1, (__float_as_uint(e.y) & 0xFFFFFC00u) | myc1);  \
                        }
                    RELAX(q0) RELAX(q1) RELAX(q2) RELAX(q3)
                    #undef RELAX
                }
                unsigned v = umin32(md0, md1);
                DPP_MIN_SHR(v, 1);
                DPP_MIN_SHR(v, 2);
                DPP_MIN_SHR(v, 4);
                DPP_MIN_SHR(v, 8);
                unsigned r0 = (unsigned)__builtin_amdgcn_readlane((int)v, 15);
                unsigned r1 = (unsigned)__builtin_amdgcn_readlane((int)v, 31);
                unsigned r2 = (unsigned)__builtin_amdgcn_readlane((int)v, 47);
                unsigned r3 = (unsigned)__builtin_amdgcn_readlane((int)v, 63);
                if (lane == 0)
                    wavemin[(step & 1) * 8 + wid] = umin32(umin32(r0, r1), umin32(r2, r3));
            }
            __syncthreads();
            if (t < HALF) {
                const uint4* wmv = (const uint4*)(wavemin + (step & 1) * 8);
                uint4 u0 = wmv[0], u1 = wmv[1];
                unsigned m0 = umin32(umin32(u0.x, u0.y), umin32(u0.z, u0.w));
                unsigned m1 = umin32(umin32(u1.x, u1.y), umin32(u1.z, u1.w));
                unsigned G = umin32(m0, m1);
                c_cur = G & 0x3FFu;
                if (t == 0)
                    S.deaths[dcbase + step] = sqrtf(__uint_as_float(G & 0xFFFFFC00u) + 1e-12f);
                if (myc0 == c_cur) { pxv2.x = INFINITY; md0 = INF32; }
                if (myc1 == c_cur) { pxv2.y = INFINITY; md1 = INF32; }
            }
        }
    }

    // ---- hybrid bitonic sort (register element; j<64 via shfl_xor, j>=64 via LDS) ----
    if (t == 0) S.deaths[N - 1] = INFINITY;
    __syncthreads();
    {
        float v = S.deaths[t];
        #pragma unroll
        for (int k = 2; k <= N; k <<= 1) {
            const bool up = ((t & k) == 0);
            #pragma unroll
            for (int j = k >> 1; j > 0; j >>= 1) {
                float uu;
                if (j >= 64) {
                    S.deaths[t] = v;
                    __syncthreads();
                    uu = S.deaths[t ^ j];
                    __syncthreads();
                } else {
                    uu = __shfl_xor(v, j, 64);
                }
                v = (((t & j) == 0) == up) ? fminf(v, uu) : fmaxf(v, uu);
            }
        }
        float* dst = ws + (size_t)blk * N;
        dst[t] = (t < N - 1) ? v : 0.0f;
    }

    // ---- last-block diff (release: fence+barrier+ticket; acquire in last block) ----
    __threadfence();
    __syncthreads();
    if (t == 0) S.ticket = (int)atomicAdd(ctr, 1u);
    __syncthreads();
    if (S.ticket == 127) {
        __threadfence();                       // acquire across XCD L2s
        const int g = t >> 8, tl = t & 255;    // 4 pair-groups of 256 threads
        float acc = 0.0f;
        for (int chunk = 0; chunk < 16; ++chunk) {
            const int b = (chunk << 2) + g;
            const float* a = ws + (size_t)b * N;
            const float* c = ws + (size_t)(64 + b) * N;
            float sum = 0.0f;
            for (int i = tl; i < N; i += 256)
                sum += fabsf(a[i] - c[i]);
            #pragma unroll
            for (int off = 32; off > 0; off >>= 1)
                sum += __shfl_down(sum, off, 64);
            if ((tl & 63) == 0) S.red4[chunk & 1][g][tl >> 6] = sum;
            __syncthreads();
            if (t == 0) {                      // ascending b: chunk-major, g-minor
                #pragma unroll
                for (int gg = 0; gg < 4; ++gg) {
                    const float* r = S.red4[chunk & 1][gg];
                    acc += (r[0] + r[1] + r[2] + r[3]) * (1.0f / 64.0f);
                }
            }
        }
        if (t == 0) out[0] = acc;
    }
}

// ======================= fallback path (small workspace): unchanged =======================
__global__ __launch_bounds__(T) void final_kernel(const float* __restrict__ gts,
                                                  const float* __restrict__ preds,
                                                  float* __restrict__ ws) {
    __shared__ float4 pts[N];
    __shared__ float4 spts[N];
    __shared__ unsigned comp[N];
    __shared__ ull bestComp[N];
    __shared__ unsigned parent[N];
    __shared__ __align__(16) unsigned pb[2][N];
    __shared__ float deaths[N];
    __shared__ unsigned wsum[16];
    __shared__ int deathCount;

    const int t = threadIdx.x;
    const int blk = blockIdx.x;
    const float* __restrict__ src = (blk < 64 ? gts : preds) + (size_t)(blk & 63) * N * 3;

    {
        float* stg = (float*)&spts[0];
        if (t < 768) ((float4*)stg)[t] = ((const float4*)src)[t];
        __syncthreads();
        float x = stg[3 * t], y = stg[3 * t + 1], z = stg[3 * t + 2];
        pts[t] = make_float4(x, y, z, __uint_as_float((unsigned)t));
        comp[t] = (unsigned)t;
        parent[t] = (unsigned)t;
        deaths[t] = 0.0f;
        bestComp[t] = INF64;
    }
    if (t == 0) deathCount = 0;
    __syncthreads();

    const int n = t & (HALF - 1);
    const int h = t >> 9;
    const int n2 = n + HALF;
    const int jbase = h * HALF;
    float4 pA = pts[n], pB = pts[n2];
    const v2f pxv = (v2f){pA.x, pB.x};
    const v2f pyv = (v2f){pA.y, pB.y};
    const v2f pzv = (v2f){pA.z, pB.z};

    int phase = 0;
    while (N - deathCount > 1 && phase < PHASE_CAP) {
        const unsigned c0 = comp[n], c1 = comp[n2];
        unsigned best0 = INF32, best1 = INF32;
        #pragma unroll 8
        for (int jj = 0; jj < HALF; ++jj) {
            int j = jbase + jj;
            float4 pj = pts[j];
            unsigned cj = __float_as_uint(pj.w);
            v2f dx = pxv - (v2f){pj.x, pj.x};
            v2f dy = pyv - (v2f){pj.y, pj.y};
            v2f dz = pzv - (v2f){pj.z, pj.z};
            v2f e = dx * dx;
            e = __builtin_elementwise_fma(dy, dy, e);
            e = __builtin_elementwise_fma(dz, dz, e);
            unsigned k0 = (__float_as_uint(e.x) & 0xFFFFF800u) | (unsigned)j;
            unsigned k1 = (__float_as_uint(e.y) & 0xFFFFF800u) | (unsigned)j;
            k0 = (cj == c0) ? INF32 : k0;
            k1 = (cj == c1) ? INF32 : k1;
            best0 = umin32(best0, k0);
            best1 = umin32(best1, k1);
        }
        pb[h][n] = best0;
        pb[h][n2] = best1;
        __syncthreads();
        if (h == 0) {
            #pragma unroll
            for (int s = 0; s < 2; ++s) {
                int m = s == 0 ? n : n2;
                unsigned fb = umin32(pb[0][m], pb[1][m]);
                if (fb != INF32) {
                    unsigned j = fb & 0x3FFu, e = fb & 0xFFFFF800u;
                    unsigned mn = umin32((unsigned)m, j), mx = umax32((unsigned)m, j);
                    ull key = ((ull)e << 20) | (ull)((mn << 10) | mx);
                    if (phase == 0) bestComp[m] = key;
                    else atomicMin(&bestComp[comp[m]], key);
                }
            }
        }
        __syncthreads();
        const unsigned c = (unsigned)t;
        const bool isRoot = (parent[c] == c);
        {
            ull bc = bestComp[c];
            if (isRoot && bc != INF64) {
                unsigned mn = (unsigned)((bc >> 10) & 0x3FFu);
                unsigned mx = (unsigned)(bc & 0x3FFu);
                unsigned cm = comp[mn];
                parent[c] = (cm == c) ? comp[mx] : cm;
            }
        }
        __syncthreads();
        {
            bool rec = false;
            float dval = 0.0f;
            unsigned p = parent[c];
            if (isRoot && p != c) {
                unsigned gp = parent[p];
                bool mutual = (gp == c);
                rec = !mutual || (c < p);
                if (rec) dval = sqrtf(__uint_as_float((unsigned)(bestComp[c] >> 20)) + 1e-12f);
            }
            ull m = __ballot(rec);
            int cnt = __popcll(m);
            int base = 0;
            if ((t & 63) == 0 && cnt) base = atomicAdd(&deathCount, cnt);
            base = __shfl(base, 0, 64);
            if (rec) {
                int idx = base + __popcll(m & ((1ull << (t & 63)) - 1ull));
                if (idx < N - 1) deaths[idx] = dval;
            }
        }
        __syncthreads();
        {
            unsigned r = walk_root(parent, c);
            parent[t] = r;
            unsigned nc = walk_root(parent, comp[t]);
            comp[t] = nc;
            pts[t].w = __uint_as_float(nc);
            bestComp[t] = INF64;
        }
        __syncthreads();
        ++phase;
    }

    if (t == 0) deaths[N - 1] = INFINITY;
    __syncthreads();
    {
        float v = deaths[t];
        #pragma unroll
        for (int k = 2; k <= N; k <<= 1) {
            const bool up = ((t & k) == 0);
            #pragma unroll
            for (int j = k >> 1; j > 0; j >>= 1) {
                float u;
                if (j >= 64) {
                    deaths[t] = v;
                    __syncthreads();
                    u = deaths[t ^ j];
                    __syncthreads();
                } else {
                    u = __shfl_xor(v, j, 64);
                }
                v = (((t & j) == 0) == up) ? fminf(v, u) : fmaxf(v, u);
            }
        }
        float* dst = ws + (size_t)blk * N;
        dst[t] = (t < N - 1) ? v : 0.0f;
    }
}

__global__ __launch_bounds__(256) void diff_kernel(const float* __restrict__ ws,
                                                   float* __restrict__ out) {
    __shared__ float red[4];
    const int t = threadIdx.x;
    const int b = blockIdx.x;
    const float* a = ws + (size_t)b * N;
    const float* c = ws + (size_t)(64 + b) * N;
    float sum = 0.0f;
    for (int i = t; i < N; i += 256)
        sum += fabsf(a[i] - c[i]);
    #pragma unroll
    for (int off = 32; off > 0; off >>= 1)
        sum += __shfl_down(sum, off, 64);
    if ((t & 63) == 0) red[t >> 6] = sum;
    __syncthreads();
    if (t == 0)
        atomicAdd(out, (red[0] + red[1] + red[2] + red[3]) * (1.0f / 64.0f));
}

extern "C" void kernel_launch(void* const* d_in, const int* in_sizes, int n_in,
                              void* d_out, int out_size, void* d_ws, size_t ws_size,
                              hipStream_t stream) {
    const float* gts = (const float*)d_in[0];
    const float* preds = (const float*)d_in[1];
    float* ws = (float*)d_ws;                     // sorted deaths at ws[0 .. 128*N)
    const bool big = ws_size >= (size_t)(2u * 128u * N * 4u);

    if (big) {
        unsigned* ctr = (unsigned*)(ws + (size_t)128 * N);   // 4B ticket counter
        hipMemsetAsync(ctr, 0, sizeof(unsigned), stream);
        hipLaunchKernelGGL(mega_kernel, dim3(128), dim3(T), 0, stream,
                           gts, preds, ws, (float*)d_out, ctr);
    } else {
        hipLaunchKernelGGL(final_kernel, dim3(128), dim3(T), 0, stream, gts, preds, ws);
        hipMemsetAsync(d_out, 0, sizeof(float), stream);
        hipLaunchKernelGGL(diff_kernel, dim3(64), dim3(256), 0, stream, ws, (float*)d_out);
    }
}

// Round 6
// 272.538 us; speedup vs baseline: 1.9039x; 1.1886x over previous
//
#include <hip/hip_runtime.h>
#include <math.h>

#define N 1024
#define T 1024           // 16 waves per block
#define HALF 512
#define PHASE_CAP 10
#define SWITCH 80        // in-block Boruvka only if comps > 80 (measured: never on this data)

typedef float v2f __attribute__((ext_vector_type(2)));
typedef unsigned long long ull;

#define INF64 0xFFFFFFFFFFFFFFFFull
#define INF32 0xFFFFFFFFu

__device__ __forceinline__ unsigned umin32(unsigned a, unsigned b) { return a < b ? a : b; }
__device__ __forceinline__ unsigned umax32(unsigned a, unsigned b) { return a > b ? a : b; }
__device__ __forceinline__ int imin32(int a, int b) { return a < b ? a : b; }

// Root walk with 2-cycle detection (keys globally distinct => cycles are exactly
// mutual pairs; root = min of the pair). Safe under concurrent parent[x] <- root(x).
__device__ __forceinline__ unsigned walk_root(const unsigned* parent, unsigned x) {
    unsigned prev = x, cur = parent[x];
    while (cur != prev) {
        unsigned nxt = parent[cur];
        if (nxt == prev) { cur = umin32(cur, prev); break; }
        prev = cur; cur = nxt;
    }
    return cur;
}

// DPP row_shr min step (row = 16 lanes), identity = 0xFFFFFFFF
#define DPP_MIN_SHR(v, sh)                                                                   \
    do {                                                                                     \
        unsigned _t = (unsigned)__builtin_amdgcn_update_dpp(                                 \
            (int)0xFFFFFFFF, (int)(v), 0x110 | (sh), 0xF, 0xF, false);                       \
        (v) = umin32((v), _t);                                                               \
    } while (0)

// ---------- phase-1 scan: 512 blocks = (cloud, node-quarter). 2 blocks/CU ----------
// Thread: 2 nodes x 128 j (q=t&127 -> nodes qr*256+q, +128; s=t>>7 -> j-slice).
// 32 waves/CU (vs 16) for latency hiding; per-CU DS/VALU totals match round-3 form.
__global__ __launch_bounds__(T) void scan1_kernel(const float* __restrict__ gts,
                                                  const float* __restrict__ preds,
                                                  unsigned* __restrict__ bests1) {
    __shared__ float px[N], py[N], pz[N];
    __shared__ float stage[3 * N];
    __shared__ unsigned pb8[8][256];
    const int t = threadIdx.x;
    const int cloud = blockIdx.x >> 2;
    const int qr = blockIdx.x & 3;
    const float* __restrict__ src = (cloud < 64 ? gts : preds) + (size_t)(cloud & 63) * N * 3;

    if (t < 768) ((float4*)stage)[t] = ((const float4*)src)[t];
    __syncthreads();
    px[t] = stage[3 * t]; py[t] = stage[3 * t + 1]; pz[t] = stage[3 * t + 2];
    __syncthreads();

    const int q = t & 127;
    const int s = t >> 7;
    const int jbase = s << 7;
    const int n0 = qr * 256 + q;
    const int n1 = n0 + 128;
    const v2f axv = (v2f){px[n0], px[n1]}, ayv = (v2f){py[n0], py[n1]},
              azv = (v2f){pz[n0], pz[n1]};
    unsigned b0 = INF32, b1 = INF32;
    #pragma unroll 4
    for (int jj = 0; jj < 128; jj += 2) {
        const int j = jbase + jj;
        v2f qx = *(const v2f*)&px[j];     // ds_read_b64, wave-uniform -> broadcast
        v2f qy = *(const v2f*)&py[j];
        v2f qz = *(const v2f*)&pz[j];
        #define STEP1(SX, SY, SZ, JV)                                                   \
        {                                                                               \
            const v2f sxv = (v2f){SX, SX}, syv = (v2f){SY, SY}, szv = (v2f){SZ, SZ};    \
            v2f dx = axv - sxv, dy = ayv - syv, dz = azv - szv;                         \
            v2f e = dx * dx;                                                            \
            e = __builtin_elementwise_fma(dy, dy, e);                                   \
            e = __builtin_elementwise_fma(dz, dz, e);                                   \
            unsigned k0 = (__float_as_uint(e.x) & 0xFFFFF800u) | (unsigned)(JV);        \
            unsigned k1 = (__float_as_uint(e.y) & 0xFFFFF800u) | (unsigned)(JV);        \
            b0 = umin32(b0, ((JV) == n0) ? INF32 : k0);                                 \
            b1 = umin32(b1, ((JV) == n1) ? INF32 : k1);                                 \
        }
        STEP1(qx.x, qy.x, qz.x, j)
        STEP1(qx.y, qy.y, qz.y, j + 1)
        #undef STEP1
    }
    pb8[s][q] = b0;
    pb8[s][q + 128] = b1;
    __syncthreads();
    if (t < 256) {
        unsigned best = umin32(umin32(pb8[0][t], pb8[1][t]), umin32(pb8[2][t], pb8[3][t]));
        best = umin32(best, umin32(umin32(pb8[4][t], pb8[5][t]), umin32(pb8[6][t], pb8[7][t])));
        bests1[(size_t)cloud * N + qr * 256 + t] = best;
    }
}

// ---------- phase-2 scan: 512 blocks; prologue rebuilds phase-1 comp labels ----------
__global__ __launch_bounds__(T) void scan2_kernel(const float* __restrict__ gts,
                                                  const float* __restrict__ preds,
                                                  const unsigned* __restrict__ bests1,
                                                  unsigned* __restrict__ bests2) {
    __shared__ float px[N], py[N], pz[N];
    __shared__ float stage[3 * N];
    __shared__ unsigned cw[N];       // comp label per node (post phase-1)
    __shared__ unsigned parent[N];
    __shared__ unsigned pb8[8][256];
    const int t = threadIdx.x;
    const int cloud = blockIdx.x >> 2;
    const int qr = blockIdx.x & 3;
    const float* __restrict__ src = (cloud < 64 ? gts : preds) + (size_t)(cloud & 63) * N * 3;

    if (t < 768) ((float4*)stage)[t] = ((const float4*)src)[t];
    __syncthreads();
    px[t] = stage[3 * t]; py[t] = stage[3 * t + 1]; pz[t] = stage[3 * t + 2];
    // merge-1 replay (labels only, no deaths): hook parent[t] = NN(t), min-rule walk
    parent[t] = bests1[(size_t)cloud * N + t] & 0x3FFu;
    __syncthreads();
    {
        unsigned r = walk_root(parent, (unsigned)t);
        parent[t] = r;
        cw[t] = r;
    }
    __syncthreads();

    const int q = t & 127;
    const int s = t >> 7;
    const int jbase = s << 7;
    const int n0 = qr * 256 + q;
    const int n1 = n0 + 128;
    const unsigned c0 = cw[n0], c1 = cw[n1];
    const v2f axv = (v2f){px[n0], px[n1]}, ayv = (v2f){py[n0], py[n1]},
              azv = (v2f){pz[n0], pz[n1]};
    unsigned b0 = INF32, b1 = INF32;
    #pragma unroll 4
    for (int jj = 0; jj < 128; jj += 2) {
        const int j = jbase + jj;
        v2f qx = *(const v2f*)&px[j];
        v2f qy = *(const v2f*)&py[j];
        v2f qz = *(const v2f*)&pz[j];
        uint2 cj = *(const uint2*)&cw[j];
        #define STEP2(SX, SY, SZ, CJ, JV)                                               \
        {                                                                               \
            const v2f sxv = (v2f){SX, SX}, syv = (v2f){SY, SY}, szv = (v2f){SZ, SZ};    \
            v2f dx = axv - sxv, dy = ayv - syv, dz = azv - szv;                         \
            v2f e = dx * dx;                                                            \
            e = __builtin_elementwise_fma(dy, dy, e);                                   \
            e = __builtin_elementwise_fma(dz, dz, e);                                   \
            unsigned k0 = (__float_as_uint(e.x) & 0xFFFFF800u) | (unsigned)(JV);        \
            unsigned k1 = (__float_as_uint(e.y) & 0xFFFFF800u) | (unsigned)(JV);        \
            b0 = umin32(b0, ((CJ) == c0) ? INF32 : k0);                                 \
            b1 = umin32(b1, ((CJ) == c1) ? INF32 : k1);                                 \
        }
        STEP2(qx.x, qy.x, qz.x, cj.x, j)
        STEP2(qx.y, qy.y, qz.y, cj.y, j + 1)
        #undef STEP2
    }
    pb8[s][q] = b0;
    pb8[s][q + 128] = b1;
    __syncthreads();
    if (t < 256) {
        unsigned best = umin32(umin32(pb8[0][t], pb8[1][t]), umin32(pb8[2][t], pb8[3][t]));
        best = umin32(best, umin32(umin32(pb8[4][t], pb8[5][t]), umin32(pb8[6][t], pb8[7][t])));
        bests2[(size_t)cloud * N + qr * 256 + t] = best;
    }
}

// ---------- final: merges + (fallback phases) + contracted Prim + sort + tail-diff ----------
// doTail != 0: out is both ticket counter (pre-zeroed) and final result; last block
// computes the diff (round-5-verified protocol).
__global__ __launch_bounds__(T) void final_kernel(const float* __restrict__ gts,
                                                  const float* __restrict__ preds,
                                                  float* __restrict__ ws,
                                                  const unsigned* __restrict__ bests1,
                                                  const unsigned* __restrict__ bests2,
                                                  int nPre,
                                                  float* __restrict__ out,
                                                  int doTail) {
    __shared__ float4 pts[N];        // x, y, z, w = comp bits
    __shared__ float4 spts[N];       // staging scratch; later comp-sorted points (Prim)
    __shared__ unsigned comp[N];
    __shared__ ull bestComp[N];      // merges: canonical best per root; Prim: segs (uint2)
    __shared__ unsigned parent[N];
    __shared__ __align__(16) unsigned pb[2][N];
    __shared__ float deaths[N];
    __shared__ unsigned wsum[16];    // counting-sort wave totals
    __shared__ int deathCount;
    __shared__ int ticketS;
    __shared__ float redT[2][4][4];  // tail-diff cells (double-buffered)

    const int t = threadIdx.x;
    const int blk = blockIdx.x;
    const float* __restrict__ src = (blk < 64 ? gts : preds) + (size_t)(blk & 63) * N * 3;

    // ---- stage + init ----
    {
        float* stg = (float*)&spts[0];
        if (t < 768) ((float4*)stg)[t] = ((const float4*)src)[t];
        __syncthreads();
        float x = stg[3 * t], y = stg[3 * t + 1], z = stg[3 * t + 2];
        pts[t] = make_float4(x, y, z, __uint_as_float((unsigned)t));
        comp[t] = (unsigned)t;
        parent[t] = (unsigned)t;
        deaths[t] = 0.0f;
        bestComp[t] = INF64;
    }
    if (t == 0) deathCount = 0;
    __syncthreads();

    const int n = t & (HALF - 1);
    const int h = t >> 9;
    const int n2 = n + HALF;
    const int jbase = h * HALF;
    float4 pA = pts[n], pB = pts[n2];
    const v2f pxv = (v2f){pA.x, pB.x};
    const v2f pyv = (v2f){pA.y, pB.y};
    const v2f pzv = (v2f){pA.z, pB.z};

    // ---- merge phase 1 from bests1 (every node is a root and hooks to its NN) ----
    if (nPre >= 1) {
        unsigned b1 = bests1[(size_t)blk * N + t];
        unsigned j1 = b1 & 0x3FFu;
        unsigned e1 = b1 & 0xFFFFF800u;
        parent[t] = j1;
        __syncthreads();
        {
            unsigned p = j1;
            unsigned gp = parent[p];
            bool mutual = (gp == (unsigned)t);
            bool rec = !mutual || ((unsigned)t < p);
            float dval = rec ? sqrtf(__uint_as_float(e1) + 1e-12f) : 0.0f;
            ull m = __ballot(rec);
            int cnt = __popcll(m);
            int base = 0;
            if ((t & 63) == 0 && cnt) base = atomicAdd(&deathCount, cnt);
            base = __shfl(base, 0, 64);
            if (rec) {
                int idx = base + __popcll(m & ((1ull << (t & 63)) - 1ull));
                if (idx < N - 1) deaths[idx] = dval;
            }
        }
        __syncthreads();
        {
            unsigned r = walk_root(parent, (unsigned)t);
            parent[t] = r;
            comp[t] = r;
            pts[t].w = __uint_as_float(r);
        }
        __syncthreads();
    }

    // ---- merge phase 2 from bests2 ----
    if (nPre >= 2) {
        unsigned b2 = bests2[(size_t)blk * N + t];
        if (b2 != INF32) {
            unsigned j2 = b2 & 0x3FFu, e2 = b2 & 0xFFFFF800u;
            unsigned mn = umin32((unsigned)t, j2), mx = umax32((unsigned)t, j2);
            atomicMin(&bestComp[comp[t]], ((ull)e2 << 20) | (ull)((mn << 10) | mx));
        }
        __syncthreads();
        const unsigned c = (unsigned)t;
        const bool isRoot = (parent[c] == c);
        {
            ull bc = bestComp[c];
            if (isRoot && bc != INF64) {
                unsigned mn = (unsigned)((bc >> 10) & 0x3FFu);
                unsigned mx = (unsigned)(bc & 0x3FFu);
                unsigned cm = comp[mn];
                parent[c] = (cm == c) ? comp[mx] : cm;
            }
        }
        __syncthreads();
        {
            bool rec = false;
            float dval = 0.0f;
            unsigned p = parent[c];
            if (isRoot && p != c) {
                unsigned gp = parent[p];
                bool mutual = (gp == c);
                rec = !mutual || (c < p);
                if (rec) dval = sqrtf(__uint_as_float((unsigned)(bestComp[c] >> 20)) + 1e-12f);
            }
            ull m = __ballot(rec);
            int cnt = __popcll(m);
            int base = 0;
            if ((t & 63) == 0 && cnt) base = atomicAdd(&deathCount, cnt);
            base = __shfl(base, 0, 64);
            if (rec) {
                int idx = base + __popcll(m & ((1ull << (t & 63)) - 1ull));
                if (idx < N - 1) deaths[idx] = dval;
            }
        }
        __syncthreads();
        {
            unsigned r = walk_root(parent, c);
            parent[t] = r;
            unsigned nc = walk_root(parent, comp[t]);
            comp[t] = nc;
            pts[t].w = __uint_as_float(nc);
            bestComp[t] = INF64;
        }
        __syncthreads();
    }

    // ---- in-kernel Boruvka phases (fallback path; never triggers on this data) ----
    int phase = nPre;
    while (N - deathCount > (nPre ? SWITCH : 1) && phase < PHASE_CAP) {
        const unsigned c0 = comp[n], c1 = comp[n2];
        unsigned best0 = INF32, best1 = INF32;
        #pragma unroll 8
        for (int jj = 0; jj < HALF; ++jj) {
            int j = jbase + jj;
            float4 pj = pts[j];
            unsigned cj = __float_as_uint(pj.w);
            v2f dx = pxv - (v2f){pj.x, pj.x};
            v2f dy = pyv - (v2f){pj.y, pj.y};
            v2f dz = pzv - (v2f){pj.z, pj.z};
            v2f e = dx * dx;
            e = __builtin_elementwise_fma(dy, dy, e);
            e = __builtin_elementwise_fma(dz, dz, e);
            unsigned k0 = (__float_as_uint(e.x) & 0xFFFFF800u) | (unsigned)j;
            unsigned k1 = (__float_as_uint(e.y) & 0xFFFFF800u) | (unsigned)j;
            k0 = (cj == c0) ? INF32 : k0;
            k1 = (cj == c1) ? INF32 : k1;
            best0 = umin32(best0, k0);
            best1 = umin32(best1, k1);
        }
        pb[h][n] = best0;
        pb[h][n2] = best1;
        __syncthreads();
        if (h == 0) {
            #pragma unroll
            for (int s = 0; s < 2; ++s) {
                int m = s == 0 ? n : n2;
                unsigned fb = umin32(pb[0][m], pb[1][m]);
                if (fb != INF32) {
                    unsigned j = fb & 0x3FFu, e = fb & 0xFFFFF800u;
                    unsigned mn = umin32((unsigned)m, j), mx = umax32((unsigned)m, j);
                    ull key = ((ull)e << 20) | (ull)((mn << 10) | mx);
                    if (phase == 0) bestComp[m] = key;
                    else atomicMin(&bestComp[comp[m]], key);
                }
            }
        }
        __syncthreads();
        const unsigned c = (unsigned)t;
        const bool isRoot = (parent[c] == c);
        {
            ull bc = bestComp[c];
            if (isRoot && bc != INF64) {
                unsigned mn = (unsigned)((bc >> 10) & 0x3FFu);
                unsigned mx = (unsigned)(bc & 0x3FFu);
                unsigned cm = comp[mn];
                parent[c] = (cm == c) ? comp[mx] : cm;
            }
        }
        __syncthreads();
        {
            bool rec = false;
            float dval = 0.0f;
            unsigned p = parent[c];
            if (isRoot && p != c) {
                unsigned gp = parent[p];
                bool mutual = (gp == c);
                rec = !mutual || (c < p);
                if (rec) dval = sqrtf(__uint_as_float((unsigned)(bestComp[c] >> 20)) + 1e-12f);
            }
            ull m = __ballot(rec);
            int cnt = __popcll(m);
            int base = 0;
            if ((t & 63) == 0 && cnt) base = atomicAdd(&deathCount, cnt);
            base = __shfl(base, 0, 64);
            if (rec) {
                int idx = base + __popcll(m & ((1ull << (t & 63)) - 1ull));
                if (idx < N - 1) deaths[idx] = dval;
            }
        }
        __syncthreads();
        {
            unsigned r = walk_root(parent, c);
            parent[t] = r;
            unsigned nc = walk_root(parent, comp[t]);
            comp[t] = nc;
            pts[t].w = __uint_as_float(nc);
            bestComp[t] = INF64;
        }
        __syncthreads();
        ++phase;
    }

    // ================= Contracted Prim on remaining comps =================
    const int dcbase = deathCount;
    const int comps = N - dcbase;
    if (comps > 1) {
        unsigned* scomp = &pb[0][0];     // comp id per sorted slot
        unsigned* hist = &pb[1][0];      // counts -> running offsets
        unsigned* wavemin = &pb[1][0];   // double-buffered: [(step&1)*8 + wid]
        uint2* segs = (uint2*)&bestComp[0];
        const int lane = t & 63;
        const int wid = t >> 6;

        hist[t] = 0;
        __syncthreads();
        atomicAdd(&hist[comp[t]], 1u);
        __syncthreads();
        unsigned cnt = hist[t];
        unsigned inc = cnt;
        #pragma unroll
        for (int d = 1; d < 64; d <<= 1) {
            unsigned u = __shfl_up(inc, d, 64);
            if (lane >= d) inc += u;
        }
        if (lane == 63) wsum[wid] = inc;
        __syncthreads();
        unsigned wof = 0;
        for (int i = 0; i < wid; ++i) wof += wsum[i];
        unsigned excl = wof + inc - cnt;
        if (cnt) { segs[t].x = excl; segs[t].y = excl + cnt; }
        __syncthreads();
        hist[t] = excl;
        __syncthreads();
        {
            unsigned pos = atomicAdd(&hist[comp[t]], 1u);
            spts[pos] = pts[t];
            scomp[pos] = comp[t];
        }
        __syncthreads();

        unsigned c_cur = comp[0];
        v2f pxv2 = (v2f){0.f, 0.f}, pyv2 = pxv2, pzv2 = pxv2;
        unsigned myc0 = 0, myc1 = 0, md0 = INF32, md1 = INF32;
        if (t < HALF) {
            float4 q0 = spts[t], q1 = spts[t + HALF];
            myc0 = scomp[t];
            myc1 = scomp[t + HALF];
            pxv2 = (v2f){q0.x, q1.x};
            pyv2 = (v2f){q0.y, q1.y};
            pzv2 = (v2f){q0.z, q1.z};
            if (myc0 == c_cur) pxv2.x = INFINITY;
            if (myc1 == c_cur) pxv2.y = INFINITY;
        }

        for (int step = 0; step < comps - 1; ++step) {
            if (t < HALF) {
                uint2 sg = segs[c_cur];
                const int jb = (int)sg.x, je = (int)sg.y, jl = je - 1;
                for (int base = jb; base < je; base += 4) {
                    float4 q0 = spts[base];
                    float4 q1 = spts[imin32(base + 1, jl)];
                    float4 q2 = spts[imin32(base + 2, jl)];
                    float4 q3 = spts[imin32(base + 3, jl)];
                    #define RELAX(qq)                                                        \
                        {                                                                    \
                            v2f dx = pxv2 - (v2f){qq.x, qq.x};                               \
                            v2f dy = pyv2 - (v2f){qq.y, qq.y};                               \
                            v2f dz = pzv2 - (v2f){qq.z, qq.z};                               \
                            v2f e = dx * dx;                                                 \
                            e = __builtin_elementwise_fma(dy, dy, e);                        \
                            e = __builtin_elementwise_fma(dz, dz, e);                        \
                            md0 = umin32(md0, (__float_as_uint(e.x) & 0xFFFFFC00u) | myc0);  \
                            md1 = umin32(md1, (__float_as_uint(e.y) & 0xFFFFFC00u) | myc1);  \
                        }
                    RELAX(q0) RELAX(q1) RELAX(q2) RELAX(q3)
                    #undef RELAX
                }
                unsigned v = umin32(md0, md1);
                DPP_MIN_SHR(v, 1);
                DPP_MIN_SHR(v, 2);
                DPP_MIN_SHR(v, 4);
                DPP_MIN_SHR(v, 8);
                unsigned r0 = (unsigned)__builtin_amdgcn_readlane((int)v, 15);
                unsigned r1 = (unsigned)__builtin_amdgcn_readlane((int)v, 31);
                unsigned r2 = (unsigned)__builtin_amdgcn_readlane((int)v, 47);
                unsigned r3 = (unsigned)__builtin_amdgcn_readlane((int)v, 63);
                if (lane == 0)
                    wavemin[(step & 1) * 8 + wid] = umin32(umin32(r0, r1), umin32(r2, r3));
            }
            __syncthreads();
            if (t < HALF) {
                const uint4* wmv = (const uint4*)(wavemin + (step & 1) * 8);
                uint4 u0 = wmv[0], u1 = wmv[1];
                unsigned m0 = umin32(umin32(u0.x, u0.y), umin32(u0.z, u0.w));
                unsigned m1 = umin32(umin32(u1.x, u1.y), umin32(u1.z, u1.w));
                unsigned G = umin32(m0, m1);
                c_cur = G & 0x3FFu;
                if (t == 0)
                    deaths[dcbase + step] = sqrtf(__uint_as_float(G & 0xFFFFFC00u) + 1e-12f);
                if (myc0 == c_cur) { pxv2.x = INFINITY; md0 = INF32; }
                if (myc1 == c_cur) { pxv2.y = INFINITY; md1 = INF32; }
            }
        }
    }

    // ---- hybrid bitonic sort (register element; j<64 via shfl_xor, j>=64 via LDS) ----
    if (t == 0) deaths[N - 1] = INFINITY;
    __syncthreads();
    {
        float v = deaths[t];
        #pragma unroll
        for (int k = 2; k <= N; k <<= 1) {
            const bool up = ((t & k) == 0);
            #pragma unroll
            for (int j = k >> 1; j > 0; j >>= 1) {
                float u;
                if (j >= 64) {
                    deaths[t] = v;
                    __syncthreads();
                    u = deaths[t ^ j];
                    __syncthreads();
                } else {
                    u = __shfl_xor(v, j, 64);
                }
                v = (((t & j) == 0) == up) ? fminf(v, u) : fmaxf(v, u);
            }
        }
        float* dst = ws + (size_t)blk * N;
        dst[t] = (t < N - 1) ? v : 0.0f;
    }

    // ---- tail diff: out doubles as ticket counter (pre-zeroed); last block diffs ----
    if (doTail) {
        __threadfence();                           // release dst
        __syncthreads();
        if (t == 0) ticketS = (int)atomicAdd((unsigned*)out, 1u);
        __syncthreads();
        if (ticketS == 127) {
            __threadfence();                       // acquire across XCD L2s
            const int g = t >> 8, tl = t & 255;    // 4 pair-groups of 256 threads
            float acc = 0.0f;
            for (int chunk = 0; chunk < 16; ++chunk) {
                const int b = (chunk << 2) + g;
                const float* a = ws + (size_t)b * N;
                const float* c = ws + (size_t)(64 + b) * N;
                float sum = 0.0f;
                for (int i = tl; i < N; i += 256)
                    sum += fabsf(a[i] - c[i]);
                #pragma unroll
                for (int off = 32; off > 0; off >>= 1)
                    sum += __shfl_down(sum, off, 64);
                if ((tl & 63) == 0) redT[chunk & 1][g][tl >> 6] = sum;
                __syncthreads();
                if (t == 0) {                      // ascending b: chunk-major, g-minor
                    #pragma unroll
                    for (int gg = 0; gg < 4; ++gg) {
                        const float* r = redT[chunk & 1][gg];
                        acc += (r[0] + r[1] + r[2] + r[3]) * (1.0f / 64.0f);
                    }
                }
            }
            if (t == 0) out[0] = acc;              // overwrite ticket with result
        }
    }
}

// Fallback diff (small-ws path only).
__global__ __launch_bounds__(256) void diff_kernel(const float* __restrict__ ws,
                                                   float* __restrict__ out) {
    __shared__ float red[4];
    const int t = threadIdx.x;
    const int b = blockIdx.x;
    const float* a = ws + (size_t)b * N;
    const float* c = ws + (size_t)(64 + b) * N;
    float sum = 0.0f;
    for (int i = t; i < N; i += 256)
        sum += fabsf(a[i] - c[i]);
    #pragma unroll
    for (int off = 32; off > 0; off >>= 1)
        sum += __shfl_down(sum, off, 64);
    if ((t & 63) == 0) red[t >> 6] = sum;
    __syncthreads();
    if (t == 0)
        atomicAdd(out, (red[0] + red[1] + red[2] + red[3]) * (1.0f / 64.0f));
}

extern "C" void kernel_launch(void* const* d_in, const int* in_sizes, int n_in,
                              void* d_out, int out_size, void* d_ws, size_t ws_size,
                              hipStream_t stream) {
    const float* gts = (const float*)d_in[0];
    const float* preds = (const float*)d_in[1];
    float* ws = (float*)d_ws;                     // sorted deaths live at ws[0 .. 128*N)
    unsigned* bests1 = (unsigned*)d_ws;           // 512 KiB (overwritten by sorted deaths)
    unsigned* bests2 = bests1 + 128 * N;          // 512 KiB
    const bool big = ws_size >= (size_t)(2u * 128u * N * 4u);

    hipMemsetAsync(d_out, 0, sizeof(float), stream);   // ticket counter / diff accumulator
    if (big) {
        hipLaunchKernelGGL(scan1_kernel, dim3(512), dim3(T), 0, stream, gts, preds, bests1);
        hipLaunchKernelGGL(scan2_kernel, dim3(512), dim3(T), 0, stream, gts, preds, bests1, bests2);
        hipLaunchKernelGGL(final_kernel, dim3(128), dim3(T), 0, stream,
                           gts, preds, ws, bests1, bests2, 2, (float*)d_out, 1);
    } else {
        hipLaunchKernelGGL(final_kernel, dim3(128), dim3(T), 0, stream,
                           gts, preds, ws, (const unsigned*)nullptr, (const unsigned*)nullptr, 0,
                           (float*)d_out, 0);
        hipLaunchKernelGGL(diff_kernel, dim3(64), dim3(256), 0, stream, ws, (float*)d_out);
    }
}

// Round 7
// 243.181 us; speedup vs baseline: 2.1338x; 1.1207x over previous
//
#include <hip/hip_runtime.h>
#include <math.h>

#define N 1024
#define T 1024           // 16 waves per block
#define HALF 512
#define PHASE_CAP 10
#define SWITCH 80        // in-block Boruvka only if comps > 80 (measured: never on this data)

typedef float v2f __attribute__((ext_vector_type(2)));
typedef unsigned long long ull;

#define INF64 0xFFFFFFFFFFFFFFFFull
#define INF32 0xFFFFFFFFu

__device__ __forceinline__ unsigned umin32(unsigned a, unsigned b) { return a < b ? a : b; }
__device__ __forceinline__ unsigned umax32(unsigned a, unsigned b) { return a > b ? a : b; }
__device__ __forceinline__ int imin32(int a, int b) { return a < b ? a : b; }

// Root walk with 2-cycle detection (keys globally distinct => cycles are exactly
// mutual pairs; root = min of the pair). Safe under concurrent parent[x] <- root(x).
__device__ __forceinline__ unsigned walk_root(const unsigned* parent, unsigned x) {
    unsigned prev = x, cur = parent[x];
    while (cur != prev) {
        unsigned nxt = parent[cur];
        if (nxt == prev) { cur = umin32(cur, prev); break; }
        prev = cur; cur = nxt;
    }
    return cur;
}

// DPP row_shr min step (row = 16 lanes), identity = 0xFFFFFFFF
#define DPP_MIN_SHR(v, sh)                                                                   \
    do {                                                                                     \
        unsigned _t = (unsigned)__builtin_amdgcn_update_dpp(                                 \
            (int)0xFFFFFFFF, (int)(v), 0x110 | (sh), 0xF, 0xF, false);                       \
        (v) = umin32((v), _t);                                                               \
    } while (0)

// ---------- phase-1 scan: 256 blocks = (cloud, node-half) ----------
// float4 LDS layout: 2 x ds_read_b128 per 2j (was 3 x b64) -> -33% DS instructions
// (DS/VALU phase-serialization theory). Arithmetic is bit-identical to round 3.
// 4 nodes x 128 j per thread.
__global__ __launch_bounds__(T) void scan1_kernel(const float* __restrict__ gts,
                                                  const float* __restrict__ preds,
                                                  unsigned* __restrict__ bests1) {
    __shared__ float4 p4[N];
    __shared__ unsigned pb8[8][HALF];       // 16 KiB; also staging scratch (12 KiB) pre-loop
    const int t = threadIdx.x;
    const int cloud = blockIdx.x >> 1;
    const int nh = blockIdx.x & 1;
    const float* __restrict__ src = (cloud < 64 ? gts : preds) + (size_t)(cloud & 63) * N * 3;

    {
        float* stg = (float*)&pb8[0][0];
        if (t < 768) ((float4*)stg)[t] = ((const float4*)src)[t];
        __syncthreads();
        p4[t] = make_float4(stg[3 * t], stg[3 * t + 1], stg[3 * t + 2], 0.0f);
        __syncthreads();
    }

    const int q = t & 127;           // node sub-id
    const int s = t >> 7;            // j-slice 0..7
    const int jbase = s << 7;
    const int n0 = nh * HALF + q;    // global node ids (4 per thread)
    const int n1 = n0 + 128, n2 = n0 + 256, n3 = n0 + 384;
    const float4 a0 = p4[n0], a1 = p4[n1], a2 = p4[n2], a3 = p4[n3];
    const v2f axA = (v2f){a0.x, a1.x}, ayA = (v2f){a0.y, a1.y}, azA = (v2f){a0.z, a1.z};
    const v2f axB = (v2f){a2.x, a3.x}, ayB = (v2f){a2.y, a3.y}, azB = (v2f){a2.z, a3.z};
    unsigned b0 = INF32, b1 = INF32, b2 = INF32, b3 = INF32;
    #pragma unroll 4
    for (int jj = 0; jj < 128; jj += 2) {
        const int j = jbase + jj;
        const float4 qa = p4[j];         // ds_read_b128, wave-uniform -> broadcast
        const float4 qb = p4[j + 1];
        #define STEP1(QQ, JV)                                                           \
        {                                                                               \
            const v2f sxv = (v2f){QQ.x, QQ.x}, syv = (v2f){QQ.y, QQ.y},                 \
                      szv = (v2f){QQ.z, QQ.z};                                          \
            v2f dxA = axA - sxv, dyA = ayA - syv, dzA = azA - szv;                      \
            v2f eA = dxA * dxA;                                                         \
            eA = __builtin_elementwise_fma(dyA, dyA, eA);                               \
            eA = __builtin_elementwise_fma(dzA, dzA, eA);                               \
            v2f dxB = axB - sxv, dyB = ayB - syv, dzB = azB - szv;                      \
            v2f eB = dxB * dxB;                                                         \
            eB = __builtin_elementwise_fma(dyB, dyB, eB);                               \
            eB = __builtin_elementwise_fma(dzB, dzB, eB);                               \
            unsigned kk;                                                                \
            kk = (__float_as_uint(eA.x) & 0xFFFFF800u) | (unsigned)(JV);                \
            b0 = umin32(b0, ((JV) == n0) ? INF32 : kk);                                 \
            kk = (__float_as_uint(eA.y) & 0xFFFFF800u) | (unsigned)(JV);                \
            b1 = umin32(b1, ((JV) == n1) ? INF32 : kk);                                 \
            kk = (__float_as_uint(eB.x) & 0xFFFFF800u) | (unsigned)(JV);                \
            b2 = umin32(b2, ((JV) == n2) ? INF32 : kk);                                 \
            kk = (__float_as_uint(eB.y) & 0xFFFFF800u) | (unsigned)(JV);                \
            b3 = umin32(b3, ((JV) == n3) ? INF32 : kk);                                 \
        }
        STEP1(qa, j)
        STEP1(qb, j + 1)
        #undef STEP1
    }
    pb8[s][q] = b0; pb8[s][q + 128] = b1; pb8[s][q + 256] = b2; pb8[s][q + 384] = b3;
    __syncthreads();
    if (t < HALF) {
        unsigned best = umin32(umin32(pb8[0][t], pb8[1][t]), umin32(pb8[2][t], pb8[3][t]));
        best = umin32(best, umin32(umin32(pb8[4][t], pb8[5][t]), umin32(pb8[6][t], pb8[7][t])));
        bests1[(size_t)cloud * N + nh * HALF + t] = best;
    }
}

// ---------- phase-2 scan: same structure; prologue rebuilds phase-1 comp labels ----------
__global__ __launch_bounds__(T) void scan2_kernel(const float* __restrict__ gts,
                                                  const float* __restrict__ preds,
                                                  const unsigned* __restrict__ bests1,
                                                  unsigned* __restrict__ bests2) {
    __shared__ float4 p4[N];
    __shared__ unsigned cw[N];       // comp label per node (post phase-1)
    __shared__ unsigned parent[N];
    __shared__ unsigned pb8[8][HALF];
    const int t = threadIdx.x;
    const int cloud = blockIdx.x >> 1;
    const int nh = blockIdx.x & 1;
    const float* __restrict__ src = (cloud < 64 ? gts : preds) + (size_t)(cloud & 63) * N * 3;

    {
        float* stg = (float*)&pb8[0][0];
        if (t < 768) ((float4*)stg)[t] = ((const float4*)src)[t];
        __syncthreads();
        p4[t] = make_float4(stg[3 * t], stg[3 * t + 1], stg[3 * t + 2], 0.0f);
    }
    // merge-1 replay (labels only, no deaths): hook parent[t] = NN(t), min-rule walk
    parent[t] = bests1[(size_t)cloud * N + t] & 0x3FFu;
    __syncthreads();
    {
        unsigned r = walk_root(parent, (unsigned)t);
        parent[t] = r;
        cw[t] = r;
    }
    __syncthreads();

    const int q = t & 127;
    const int s = t >> 7;
    const int jbase = s << 7;
    const int n0 = nh * HALF + q;
    const int n1 = n0 + 128, n2 = n0 + 256, n3 = n0 + 384;
    const unsigned c0 = cw[n0], c1 = cw[n1], c2 = cw[n2], c3 = cw[n3];
    const float4 a0 = p4[n0], a1 = p4[n1], a2 = p4[n2], a3 = p4[n3];
    const v2f axA = (v2f){a0.x, a1.x}, ayA = (v2f){a0.y, a1.y}, azA = (v2f){a0.z, a1.z};
    const v2f axB = (v2f){a2.x, a3.x}, ayB = (v2f){a2.y, a3.y}, azB = (v2f){a2.z, a3.z};
    unsigned b0 = INF32, b1 = INF32, b2 = INF32, b3 = INF32;
    #pragma unroll 4
    for (int jj = 0; jj < 128; jj += 2) {
        const int j = jbase + jj;
        const float4 qa = p4[j];
        const float4 qb = p4[j + 1];
        uint2 cj = *(const uint2*)&cw[j];
        #define STEP2(QQ, CJ, JV)                                                       \
        {                                                                               \
            const v2f sxv = (v2f){QQ.x, QQ.x}, syv = (v2f){QQ.y, QQ.y},                 \
                      szv = (v2f){QQ.z, QQ.z};                                          \
            v2f dxA = axA - sxv, dyA = ayA - syv, dzA = azA - szv;                      \
            v2f eA = dxA * dxA;                                                         \
            eA = __builtin_elementwise_fma(dyA, dyA, eA);                               \
            eA = __builtin_elementwise_fma(dzA, dzA, eA);                               \
            v2f dxB = axB - sxv, dyB = ayB - syv, dzB = azB - szv;                      \
            v2f eB = dxB * dxB;                                                         \
            eB = __builtin_elementwise_fma(dyB, dyB, eB);                               \
            eB = __builtin_elementwise_fma(dzB, dzB, eB);                               \
            unsigned kk;                                                                \
            kk = (__float_as_uint(eA.x) & 0xFFFFF800u) | (unsigned)(JV);                \
            b0 = umin32(b0, ((CJ) == c0) ? INF32 : kk);                                 \
            kk = (__float_as_uint(eA.y) & 0xFFFFF800u) | (unsigned)(JV);                \
            b1 = umin32(b1, ((CJ) == c1) ? INF32 : kk);                                 \
            kk = (__float_as_uint(eB.x) & 0xFFFFF800u) | (unsigned)(JV);                \
            b2 = umin32(b2, ((CJ) == c2) ? INF32 : kk);                                 \
            kk = (__float_as_uint(eB.y) & 0xFFFFF800u) | (unsigned)(JV);                \
            b3 = umin32(b3, ((CJ) == c3) ? INF32 : kk);                                 \
        }
        STEP2(qa, cj.x, j)
        STEP2(qb, cj.y, j + 1)
        #undef STEP2
    }
    pb8[s][q] = b0; pb8[s][q + 128] = b1; pb8[s][q + 256] = b2; pb8[s][q + 384] = b3;
    __syncthreads();
    if (t < HALF) {
        unsigned best = umin32(umin32(pb8[0][t], pb8[1][t]), umin32(pb8[2][t], pb8[3][t]));
        best = umin32(best, umin32(umin32(pb8[4][t], pb8[5][t]), umin32(pb8[6][t], pb8[7][t])));
        bests2[(size_t)cloud * N + nh * HALF + t] = best;
    }
}

// ---------- final: merges + (fallback phases) + contracted Prim + sort (r3-exact) ----------
__global__ __launch_bounds__(T) void final_kernel(const float* __restrict__ gts,
                                                  const float* __restrict__ preds,
                                                  float* __restrict__ ws,
                                                  const unsigned* __restrict__ bests1,
                                                  const unsigned* __restrict__ bests2,
                                                  int nPre) {
    __shared__ float4 pts[N];        // x, y, z, w = comp bits
    __shared__ float4 spts[N];       // staging scratch; later comp-sorted points (Prim)
    __shared__ unsigned comp[N];
    __shared__ ull bestComp[N];      // merges: canonical best per root; Prim: segs (uint2)
    __shared__ unsigned parent[N];
    __shared__ __align__(16) unsigned pb[2][N];
    __shared__ float deaths[N];
    __shared__ unsigned wsum[16];    // counting-sort wave totals
    __shared__ int deathCount;

    const int t = threadIdx.x;
    const int blk = blockIdx.x;
    const float* __restrict__ src = (blk < 64 ? gts : preds) + (size_t)(blk & 63) * N * 3;

    // ---- stage + init ----
    {
        float* stg = (float*)&spts[0];
        if (t < 768) ((float4*)stg)[t] = ((const float4*)src)[t];
        __syncthreads();
        float x = stg[3 * t], y = stg[3 * t + 1], z = stg[3 * t + 2];
        pts[t] = make_float4(x, y, z, __uint_as_float((unsigned)t));
        comp[t] = (unsigned)t;
        parent[t] = (unsigned)t;
        deaths[t] = 0.0f;
        bestComp[t] = INF64;
    }
    if (t == 0) deathCount = 0;
    __syncthreads();

    const int n = t & (HALF - 1);
    const int h = t >> 9;
    const int n2 = n + HALF;
    const int jbase = h * HALF;
    float4 pA = pts[n], pB = pts[n2];
    const v2f pxv = (v2f){pA.x, pB.x};
    const v2f pyv = (v2f){pA.y, pB.y};
    const v2f pzv = (v2f){pA.z, pB.z};

    // ---- merge phase 1 from bests1 (every node is a root and hooks to its NN) ----
    if (nPre >= 1) {
        unsigned b1 = bests1[(size_t)blk * N + t];
        unsigned j1 = b1 & 0x3FFu;
        unsigned e1 = b1 & 0xFFFFF800u;
        parent[t] = j1;
        __syncthreads();
        {
            unsigned p = j1;
            unsigned gp = parent[p];
            bool mutual = (gp == (unsigned)t);
            bool rec = !mutual || ((unsigned)t < p);
            float dval = rec ? sqrtf(__uint_as_float(e1) + 1e-12f) : 0.0f;
            ull m = __ballot(rec);
            int cnt = __popcll(m);
            int base = 0;
            if ((t & 63) == 0 && cnt) base = atomicAdd(&deathCount, cnt);
            base = __shfl(base, 0, 64);
            if (rec) {
                int idx = base + __popcll(m & ((1ull << (t & 63)) - 1ull));
                if (idx < N - 1) deaths[idx] = dval;
            }
        }
        __syncthreads();
        {
            unsigned r = walk_root(parent, (unsigned)t);
            parent[t] = r;
            comp[t] = r;
            pts[t].w = __uint_as_float(r);
        }
        __syncthreads();
    }

    // ---- merge phase 2 from bests2 ----
    if (nPre >= 2) {
        unsigned b2 = bests2[(size_t)blk * N + t];
        if (b2 != INF32) {
            unsigned j2 = b2 & 0x3FFu, e2 = b2 & 0xFFFFF800u;
            unsigned mn = umin32((unsigned)t, j2), mx = umax32((unsigned)t, j2);
            atomicMin(&bestComp[comp[t]], ((ull)e2 << 20) | (ull)((mn << 10) | mx));
        }
        __syncthreads();
        const unsigned c = (unsigned)t;
        const bool isRoot = (parent[c] == c);
        {
            ull bc = bestComp[c];
            if (isRoot && bc != INF64) {
                unsigned mn = (unsigned)((bc >> 10) & 0x3FFu);
                unsigned mx = (unsigned)(bc & 0x3FFu);
                unsigned cm = comp[mn];
                parent[c] = (cm == c) ? comp[mx] : cm;
            }
        }
        __syncthreads();
        {
            bool rec = false;
            float dval = 0.0f;
            unsigned p = parent[c];
            if (isRoot && p != c) {
                unsigned gp = parent[p];
                bool mutual = (gp == c);
                rec = !mutual || (c < p);
                if (rec) dval = sqrtf(__uint_as_float((unsigned)(bestComp[c] >> 20)) + 1e-12f);
            }
            ull m = __ballot(rec);
            int cnt = __popcll(m);
            int base = 0;
            if ((t & 63) == 0 && cnt) base = atomicAdd(&deathCount, cnt);
            base = __shfl(base, 0, 64);
            if (rec) {
                int idx = base + __popcll(m & ((1ull << (t & 63)) - 1ull));
                if (idx < N - 1) deaths[idx] = dval;
            }
        }
        __syncthreads();
        {
            unsigned r = walk_root(parent, c);
            parent[t] = r;
            unsigned nc = walk_root(parent, comp[t]);
            comp[t] = nc;
            pts[t].w = __uint_as_float(nc);
            bestComp[t] = INF64;
        }
        __syncthreads();
    }

    // ---- in-kernel Boruvka phases (fallback path; never triggers on this data) ----
    int phase = nPre;
    while (N - deathCount > (nPre ? SWITCH : 1) && phase < PHASE_CAP) {
        const unsigned c0 = comp[n], c1 = comp[n2];
        unsigned best0 = INF32, best1 = INF32;
        #pragma unroll 8
        for (int jj = 0; jj < HALF; ++jj) {
            int j = jbase + jj;
            float4 pj = pts[j];
            unsigned cj = __float_as_uint(pj.w);
            v2f dx = pxv - (v2f){pj.x, pj.x};
            v2f dy = pyv - (v2f){pj.y, pj.y};
            v2f dz = pzv - (v2f){pj.z, pj.z};
            v2f e = dx * dx;
            e = __builtin_elementwise_fma(dy, dy, e);
            e = __builtin_elementwise_fma(dz, dz, e);
            unsigned k0 = (__float_as_uint(e.x) & 0xFFFFF800u) | (unsigned)j;
            unsigned k1 = (__float_as_uint(e.y) & 0xFFFFF800u) | (unsigned)j;
            k0 = (cj == c0) ? INF32 : k0;
            k1 = (cj == c1) ? INF32 : k1;
            best0 = umin32(best0, k0);
            best1 = umin32(best1, k1);
        }
        pb[h][n] = best0;
        pb[h][n2] = best1;
        __syncthreads();
        if (h == 0) {
            #pragma unroll
            for (int s = 0; s < 2; ++s) {
                int m = s == 0 ? n : n2;
                unsigned fb = umin32(pb[0][m], pb[1][m]);
                if (fb != INF32) {
                    unsigned j = fb & 0x3FFu, e = fb & 0xFFFFF800u;
                    unsigned mn = umin32((unsigned)m, j), mx = umax32((unsigned)m, j);
                    ull key = ((ull)e << 20) | (ull)((mn << 10) | mx);
                    if (phase == 0) bestComp[m] = key;
                    else atomicMin(&bestComp[comp[m]], key);
                }
            }
        }
        __syncthreads();
        const unsigned c = (unsigned)t;
        const bool isRoot = (parent[c] == c);
        {
            ull bc = bestComp[c];
            if (isRoot && bc != INF64) {
                unsigned mn = (unsigned)((bc >> 10) & 0x3FFu);
                unsigned mx = (unsigned)(bc & 0x3FFu);
                unsigned cm = comp[mn];
                parent[c] = (cm == c) ? comp[mx] : cm;
            }
        }
        __syncthreads();
        {
            bool rec = false;
            float dval = 0.0f;
            unsigned p = parent[c];
            if (isRoot && p != c) {
                unsigned gp = parent[p];
                bool mutual = (gp == c);
                rec = !mutual || (c < p);
                if (rec) dval = sqrtf(__uint_as_float((unsigned)(bestComp[c] >> 20)) + 1e-12f);
            }
            ull m = __ballot(rec);
            int cnt = __popcll(m);
            int base = 0;
            if ((t & 63) == 0 && cnt) base = atomicAdd(&deathCount, cnt);
            base = __shfl(base, 0, 64);
            if (rec) {
                int idx = base + __popcll(m & ((1ull << (t & 63)) - 1ull));
                if (idx < N - 1) deaths[idx] = dval;
            }
        }
        __syncthreads();
        {
            unsigned r = walk_root(parent, c);
            parent[t] = r;
            unsigned nc = walk_root(parent, comp[t]);
            comp[t] = nc;
            pts[t].w = __uint_as_float(nc);
            bestComp[t] = INF64;
        }
        __syncthreads();
        ++phase;
    }

    // ================= Contracted Prim on remaining comps =================
    const int dcbase = deathCount;
    const int comps = N - dcbase;
    if (comps > 1) {
        unsigned* scomp = &pb[0][0];     // comp id per sorted slot
        unsigned* hist = &pb[1][0];      // counts -> running offsets
        unsigned* wavemin = &pb[1][0];   // double-buffered: [(step&1)*8 + wid]
        uint2* segs = (uint2*)&bestComp[0];
        const int lane = t & 63;
        const int wid = t >> 6;

        hist[t] = 0;
        __syncthreads();
        atomicAdd(&hist[comp[t]], 1u);
        __syncthreads();
        unsigned cnt = hist[t];
        unsigned inc = cnt;
        #pragma unroll
        for (int d = 1; d < 64; d <<= 1) {
            unsigned u = __shfl_up(inc, d, 64);
            if (lane >= d) inc += u;
        }
        if (lane == 63) wsum[wid] = inc;
        __syncthreads();
        unsigned wof = 0;
        for (int i = 0; i < wid; ++i) wof += wsum[i];
        unsigned excl = wof + inc - cnt;
        if (cnt) { segs[t].x = excl; segs[t].y = excl + cnt; }
        __syncthreads();
        hist[t] = excl;
        __syncthreads();
        {
            unsigned pos = atomicAdd(&hist[comp[t]], 1u);
            spts[pos] = pts[t];
            scomp[pos] = comp[t];
        }
        __syncthreads();

        unsigned c_cur = comp[0];
        v2f pxv2 = (v2f){0.f, 0.f}, pyv2 = pxv2, pzv2 = pxv2;
        unsigned myc0 = 0, myc1 = 0, md0 = INF32, md1 = INF32;
        if (t < HALF) {
            float4 q0 = spts[t], q1 = spts[t + HALF];
            myc0 = scomp[t];
            myc1 = scomp[t + HALF];
            pxv2 = (v2f){q0.x, q1.x};
            pyv2 = (v2f){q0.y, q1.y};
            pzv2 = (v2f){q0.z, q1.z};
            if (myc0 == c_cur) pxv2.x = INFINITY;
            if (myc1 == c_cur) pxv2.y = INFINITY;
        }

        for (int step = 0; step < comps - 1; ++step) {
            if (t < HALF) {
                uint2 sg = segs[c_cur];
                const int jb = (int)sg.x, je = (int)sg.y, jl = je - 1;
                for (int base = jb; base < je; base += 4) {
                    float4 q0 = spts[base];
                    float4 q1 = spts[imin32(base + 1, jl)];
                    float4 q2 = spts[imin32(base + 2, jl)];
                    float4 q3 = spts[imin32(base + 3, jl)];
                    #define RELAX(qq)                                                        \
                        {                                                                    \
                            v2f dx = pxv2 - (v2f){qq.x, qq.x};                               \
                            v2f dy = pyv2 - (v2f){qq.y, qq.y};                               \
                            v2f dz = pzv2 - (v2f){qq.z, qq.z};                               \
                            v2f e = dx * dx;                                                 \
                            e = __builtin_elementwise_fma(dy, dy, e);                        \
                            e = __builtin_elementwise_fma(dz, dz, e);                        \
                            md0 = umin32(md0, (__float_as_uint(e.x) & 0xFFFFFC00u) | myc0);  \
                            md1 = umin32(md1, (__float_as_uint(e.y) & 0xFFFFFC00u) | myc1);  \
                        }
                    RELAX(q0) RELAX(q1) RELAX(q2) RELAX(q3)
                    #undef RELAX
                }
                unsigned v = umin32(md0, md1);
                DPP_MIN_SHR(v, 1);
                DPP_MIN_SHR(v, 2);
                DPP_MIN_SHR(v, 4);
                DPP_MIN_SHR(v, 8);
                unsigned r0 = (unsigned)__builtin_amdgcn_readlane((int)v, 15);
                unsigned r1 = (unsigned)__builtin_amdgcn_readlane((int)v, 31);
                unsigned r2 = (unsigned)__builtin_amdgcn_readlane((int)v, 47);
                unsigned r3 = (unsigned)__builtin_amdgcn_readlane((int)v, 63);
                if (lane == 0)
                    wavemin[(step & 1) * 8 + wid] = umin32(umin32(r0, r1), umin32(r2, r3));
            }
            __syncthreads();                     // single barrier per step (dbuf-safe)
            if (t < HALF) {
                const uint4* wmv = (const uint4*)(wavemin + (step & 1) * 8);
                uint4 u0 = wmv[0], u1 = wmv[1];
                unsigned m0 = umin32(umin32(u0.x, u0.y), umin32(u0.z, u0.w));
                unsigned m1 = umin32(umin32(u1.x, u1.y), umin32(u1.z, u1.w));
                unsigned G = umin32(m0, m1);
                c_cur = G & 0x3FFu;
                if (t == 0)
                    deaths[dcbase + step] = sqrtf(__uint_as_float(G & 0xFFFFFC00u) + 1e-12f);
                if (myc0 == c_cur) { pxv2.x = INFINITY; md0 = INF32; }
                if (myc1 == c_cur) { pxv2.y = INFINITY; md1 = INF32; }
            }
        }
    }

    // ---- hybrid bitonic sort (register element; j<64 via shfl_xor, j>=64 via LDS) ----
    if (t == 0) deaths[N - 1] = INFINITY;
    __syncthreads();
    {
        float v = deaths[t];
        #pragma unroll
        for (int k = 2; k <= N; k <<= 1) {
            const bool up = ((t & k) == 0);
            #pragma unroll
            for (int j = k >> 1; j > 0; j >>= 1) {
                float u;
                if (j >= 64) {
                    deaths[t] = v;
                    __syncthreads();
                    u = deaths[t ^ j];
                    __syncthreads();
                } else {
                    u = __shfl_xor(v, j, 64);
                }
                v = (((t & j) == 0) == up) ? fminf(v, u) : fmaxf(v, u);
            }
        }
        float* dst = ws + (size_t)blk * N;
        dst[t] = (t < N - 1) ? v : 0.0f;
    }
}

// Single-block diff: r5/r6-proven shape (same per-pair decomposition as the old
// 64-block diff, ascending accumulate) as a standalone kernel -> no fences, no
// memset, direct write to out.
__global__ __launch_bounds__(T) void diff1_kernel(const float* __restrict__ ws,
                                                  float* __restrict__ out) {
    __shared__ float red[2][4][4];
    const int t = threadIdx.x;
    const int g = t >> 8, tl = t & 255;        // 4 pair-groups of 256 threads
    float acc = 0.0f;
    for (int chunk = 0; chunk < 16; ++chunk) {
        const int b = (chunk << 2) + g;
        const float* a = ws + (size_t)b * N;
        const float* c = ws + (size_t)(64 + b) * N;
        float sum = 0.0f;
        for (int i = tl; i < N; i += 256)
            sum += fabsf(a[i] - c[i]);
        #pragma unroll
        for (int off = 32; off > 0; off >>= 1)
            sum += __shfl_down(sum, off, 64);
        if ((tl & 63) == 0) red[chunk & 1][g][tl >> 6] = sum;
        __syncthreads();
        if (t == 0) {                          // ascending b: chunk-major, g-minor
            #pragma unroll
            for (int gg = 0; gg < 4; ++gg) {
                const float* r = red[chunk & 1][gg];
                acc += (r[0] + r[1] + r[2] + r[3]) * (1.0f / 64.0f);
            }
        }
    }
    if (t == 0) out[0] = acc;
}

// Fallback diff (small-ws path only).
__global__ __launch_bounds__(256) void diff_kernel(const float* __restrict__ ws,
                                                   float* __restrict__ out) {
    __shared__ float red[4];
    const int t = threadIdx.x;
    const int b = blockIdx.x;
    const float* a = ws + (size_t)b * N;
    const float* c = ws + (size_t)(64 + b) * N;
    float sum = 0.0f;
    for (int i = t; i < N; i += 256)
        sum += fabsf(a[i] - c[i]);
    #pragma unroll
    for (int off = 32; off > 0; off >>= 1)
        sum += __shfl_down(sum, off, 64);
    if ((t & 63) == 0) red[t >> 6] = sum;
    __syncthreads();
    if (t == 0)
        atomicAdd(out, (red[0] + red[1] + red[2] + red[3]) * (1.0f / 64.0f));
}

extern "C" void kernel_launch(void* const* d_in, const int* in_sizes, int n_in,
                              void* d_out, int out_size, void* d_ws, size_t ws_size,
                              hipStream_t stream) {
    const float* gts = (const float*)d_in[0];
    const float* preds = (const float*)d_in[1];
    float* ws = (float*)d_ws;                     // sorted deaths live at ws[0 .. 128*N)
    unsigned* bests1 = (unsigned*)d_ws;           // 512 KiB (overwritten by sorted deaths)
    unsigned* bests2 = bests1 + 128 * N;          // 512 KiB
    const bool big = ws_size >= (size_t)(2u * 128u * N * 4u);

    if (big) {
        hipLaunchKernelGGL(scan1_kernel, dim3(256), dim3(T), 0, stream, gts, preds, bests1);
        hipLaunchKernelGGL(scan2_kernel, dim3(256), dim3(T), 0, stream, gts, preds, bests1, bests2);
        hipLaunchKernelGGL(final_kernel, dim3(128), dim3(T), 0, stream,
                           gts, preds, ws, bests1, bests2, 2);
        hipLaunchKernelGGL(diff1_kernel, dim3(1), dim3(T), 0, stream, ws, (float*)d_out);
    } else {
        hipLaunchKernelGGL(final_kernel, dim3(128), dim3(T), 0, stream,
                           gts, preds, ws, (const unsigned*)nullptr, (const unsigned*)nullptr, 0);
        hipMemsetAsync(d_out, 0, sizeof(float), stream);
        hipLaunchKernelGGL(diff_kernel, dim3(64), dim3(256), 0, stream, ws, (float*)d_out);
    }
}

// Round 8
// 218.184 us; speedup vs baseline: 2.3782x; 1.1146x over previous
//
#include <hip/hip_runtime.h>
#include <math.h>

#define N 1024
#define T 1024           // 16 waves per block
#define HALF 512
#define PHASE_CAP 10
#define SWITCH 80        // in-block Boruvka only if comps > 80 (measured: never on this data)

typedef float v2f __attribute__((ext_vector_type(2)));
typedef unsigned long long ull;

#define INF64 0xFFFFFFFFFFFFFFFFull
#define INF32 0xFFFFFFFFu

__device__ __forceinline__ unsigned umin32(unsigned a, unsigned b) { return a < b ? a : b; }
__device__ __forceinline__ unsigned umax32(unsigned a, unsigned b) { return a > b ? a : b; }
__device__ __forceinline__ int imin32(int a, int b) { return a < b ? a : b; }

// Root walk with 2-cycle detection (keys globally distinct => cycles are exactly
// mutual pairs; root = min of the pair). Safe under concurrent parent[x] <- root(x).
__device__ __forceinline__ unsigned walk_root(const unsigned* parent, unsigned x) {
    unsigned prev = x, cur = parent[x];
    while (cur != prev) {
        unsigned nxt = parent[cur];
        if (nxt == prev) { cur = umin32(cur, prev); break; }
        prev = cur; cur = nxt;
    }
    return cur;
}

// DPP row_shr min step (row = 16 lanes), identity = 0xFFFFFFFF
#define DPP_MIN_SHR(v, sh)                                                                   \
    do {                                                                                     \
        unsigned _t = (unsigned)__builtin_amdgcn_update_dpp(                                 \
            (int)0xFFFFFFFF, (int)(v), 0x110 | (sh), 0xF, 0xF, false);                       \
        (v) = umin32((v), _t);                                                               \
    } while (0)

// ---------- phase-1 scan: 256 blocks = (cloud, node-half) ----------
// float4 LDS layout: 2 x ds_read_b128 per 2j. 4 nodes x 128 j per thread.
__global__ __launch_bounds__(T) void scan1_kernel(const float* __restrict__ gts,
                                                  const float* __restrict__ preds,
                                                  unsigned* __restrict__ bests1) {
    __shared__ float4 p4[N];
    __shared__ unsigned pb8[8][HALF];       // 16 KiB; also staging scratch (12 KiB) pre-loop
    const int t = threadIdx.x;
    const int cloud = blockIdx.x >> 1;
    const int nh = blockIdx.x & 1;
    const float* __restrict__ src = (cloud < 64 ? gts : preds) + (size_t)(cloud & 63) * N * 3;

    {
        float* stg = (float*)&pb8[0][0];
        if (t < 768) ((float4*)stg)[t] = ((const float4*)src)[t];
        __syncthreads();
        p4[t] = make_float4(stg[3 * t], stg[3 * t + 1], stg[3 * t + 2], 0.0f);
        __syncthreads();
    }

    const int q = t & 127;           // node sub-id
    const int s = t >> 7;            // j-slice 0..7
    const int jbase = s << 7;
    const int n0 = nh * HALF + q;    // global node ids (4 per thread)
    const int n1 = n0 + 128, n2 = n0 + 256, n3 = n0 + 384;
    const float4 a0 = p4[n0], a1 = p4[n1], a2 = p4[n2], a3 = p4[n3];
    const v2f axA = (v2f){a0.x, a1.x}, ayA = (v2f){a0.y, a1.y}, azA = (v2f){a0.z, a1.z};
    const v2f axB = (v2f){a2.x, a3.x}, ayB = (v2f){a2.y, a3.y}, azB = (v2f){a2.z, a3.z};
    unsigned b0 = INF32, b1 = INF32, b2 = INF32, b3 = INF32;
    #pragma unroll 4
    for (int jj = 0; jj < 128; jj += 2) {
        const int j = jbase + jj;
        const float4 qa = p4[j];         // ds_read_b128, wave-uniform -> broadcast
        const float4 qb = p4[j + 1];
        #define STEP1(QQ, JV)                                                           \
        {                                                                               \
            const v2f sxv = (v2f){QQ.x, QQ.x}, syv = (v2f){QQ.y, QQ.y},                 \
                      szv = (v2f){QQ.z, QQ.z};                                          \
            v2f dxA = axA - sxv, dyA = ayA - syv, dzA = azA - szv;                      \
            v2f eA = dxA * dxA;                                                         \
            eA = __builtin_elementwise_fma(dyA, dyA, eA);                               \
            eA = __builtin_elementwise_fma(dzA, dzA, eA);                               \
            v2f dxB = axB - sxv, dyB = ayB - syv, dzB = azB - szv;                      \
            v2f eB = dxB * dxB;                                                         \
            eB = __builtin_elementwise_fma(dyB, dyB, eB);                               \
            eB = __builtin_elementwise_fma(dzB, dzB, eB);                               \
            unsigned kk;                                                                \
            kk = (__float_as_uint(eA.x) & 0xFFFFF800u) | (unsigned)(JV);                \
            b0 = umin32(b0, ((JV) == n0) ? INF32 : kk);                                 \
            kk = (__float_as_uint(eA.y) & 0xFFFFF800u) | (unsigned)(JV);                \
            b1 = umin32(b1, ((JV) == n1) ? INF32 : kk);                                 \
            kk = (__float_as_uint(eB.x) & 0xFFFFF800u) | (unsigned)(JV);                \
            b2 = umin32(b2, ((JV) == n2) ? INF32 : kk);                                 \
            kk = (__float_as_uint(eB.y) & 0xFFFFF800u) | (unsigned)(JV);                \
            b3 = umin32(b3, ((JV) == n3) ? INF32 : kk);                                 \
        }
        STEP1(qa, j)
        STEP1(qb, j + 1)
        #undef STEP1
    }
    pb8[s][q] = b0; pb8[s][q + 128] = b1; pb8[s][q + 256] = b2; pb8[s][q + 384] = b3;
    __syncthreads();
    if (t < HALF) {
        unsigned best = umin32(umin32(pb8[0][t], pb8[1][t]), umin32(pb8[2][t], pb8[3][t]));
        best = umin32(best, umin32(umin32(pb8[4][t], pb8[5][t]), umin32(pb8[6][t], pb8[7][t])));
        bests1[(size_t)cloud * N + nh * HALF + t] = best;
    }
}

// ---------- phase-2 scan: same structure; prologue rebuilds phase-1 comp labels ----------
__global__ __launch_bounds__(T) void scan2_kernel(const float* __restrict__ gts,
                                                  const float* __restrict__ preds,
                                                  const unsigned* __restrict__ bests1,
                                                  unsigned* __restrict__ bests2) {
    __shared__ float4 p4[N];
    __shared__ unsigned cw[N];       // comp label per node (post phase-1)
    __shared__ unsigned parent[N];
    __shared__ unsigned pb8[8][HALF];
    const int t = threadIdx.x;
    const int cloud = blockIdx.x >> 1;
    const int nh = blockIdx.x & 1;
    const float* __restrict__ src = (cloud < 64 ? gts : preds) + (size_t)(cloud & 63) * N * 3;

    {
        float* stg = (float*)&pb8[0][0];
        if (t < 768) ((float4*)stg)[t] = ((const float4*)src)[t];
        __syncthreads();
        p4[t] = make_float4(stg[3 * t], stg[3 * t + 1], stg[3 * t + 2], 0.0f);
    }
    // merge-1 replay (labels only, no deaths): hook parent[t] = NN(t), min-rule walk
    parent[t] = bests1[(size_t)cloud * N + t] & 0x3FFu;
    __syncthreads();
    {
        unsigned r = walk_root(parent, (unsigned)t);
        parent[t] = r;
        cw[t] = r;
    }
    __syncthreads();

    const int q = t & 127;
    const int s = t >> 7;
    const int jbase = s << 7;
    const int n0 = nh * HALF + q;
    const int n1 = n0 + 128, n2 = n0 + 256, n3 = n0 + 384;
    const unsigned c0 = cw[n0], c1 = cw[n1], c2 = cw[n2], c3 = cw[n3];
    const float4 a0 = p4[n0], a1 = p4[n1], a2 = p4[n2], a3 = p4[n3];
    const v2f axA = (v2f){a0.x, a1.x}, ayA = (v2f){a0.y, a1.y}, azA = (v2f){a0.z, a1.z};
    const v2f axB = (v2f){a2.x, a3.x}, ayB = (v2f){a2.y, a3.y}, azB = (v2f){a2.z, a3.z};
    unsigned b0 = INF32, b1 = INF32, b2 = INF32, b3 = INF32;
    #pragma unroll 4
    for (int jj = 0; jj < 128; jj += 2) {
        const int j = jbase + jj;
        const float4 qa = p4[j];
        const float4 qb = p4[j + 1];
        uint2 cj = *(const uint2*)&cw[j];
        #define STEP2(QQ, CJ, JV)                                                       \
        {                                                                               \
            const v2f sxv = (v2f){QQ.x, QQ.x}, syv = (v2f){QQ.y, QQ.y},                 \
                      szv = (v2f){QQ.z, QQ.z};                                          \
            v2f dxA = axA - sxv, dyA = ayA - syv, dzA = azA - szv;                      \
            v2f eA = dxA * dxA;                                                         \
            eA = __builtin_elementwise_fma(dyA, dyA, eA);                               \
            eA = __builtin_elementwise_fma(dzA, dzA, eA);                               \
            v2f dxB = axB - sxv, dyB = ayB - syv, dzB = azB - szv;                      \
            v2f eB = dxB * dxB;                                                         \
            eB = __builtin_elementwise_fma(dyB, dyB, eB);                               \
            eB = __builtin_elementwise_fma(dzB, dzB, eB);                               \
            unsigned kk;                                                                \
            kk = (__float_as_uint(eA.x) & 0xFFFFF800u) | (unsigned)(JV);                \
            b0 = umin32(b0, ((CJ) == c0) ? INF32 : kk);                                 \
            kk = (__float_as_uint(eA.y) & 0xFFFFF800u) | (unsigned)(JV);                \
            b1 = umin32(b1, ((CJ) == c1) ? INF32 : kk);                                 \
            kk = (__float_as_uint(eB.x) & 0xFFFFF800u) | (unsigned)(JV);                \
            b2 = umin32(b2, ((CJ) == c2) ? INF32 : kk);                                 \
            kk = (__float_as_uint(eB.y) & 0xFFFFF800u) | (unsigned)(JV);                \
            b3 = umin32(b3, ((CJ) == c3) ? INF32 : kk);                                 \
        }
        STEP2(qa, cj.x, j)
        STEP2(qb, cj.y, j + 1)
        #undef STEP2
    }
    pb8[s][q] = b0; pb8[s][q + 128] = b1; pb8[s][q + 256] = b2; pb8[s][q + 384] = b3;
    __syncthreads();
    if (t < HALF) {
        unsigned best = umin32(umin32(pb8[0][t], pb8[1][t]), umin32(pb8[2][t], pb8[3][t]));
        best = umin32(best, umin32(umin32(pb8[4][t], pb8[5][t]), umin32(pb8[6][t], pb8[7][t])));
        bests2[(size_t)cloud * N + nh * HALF + t] = best;
    }
}

// ---------- final: merges + (fallback phases) + contracted Prim + sort (r3-exact) ----------
__global__ __launch_bounds__(T) void final_kernel(const float* __restrict__ gts,
                                                  const float* __restrict__ preds,
                                                  float* __restrict__ ws,
                                                  const unsigned* __restrict__ bests1,
                                                  const unsigned* __restrict__ bests2,
                                                  int nPre) {
    __shared__ float4 pts[N];        // x, y, z, w = comp bits
    __shared__ float4 spts[N];       // staging scratch; later comp-sorted points (Prim)
    __shared__ unsigned comp[N];
    __shared__ ull bestComp[N];      // merges: canonical best per root; Prim: segs (uint2)
    __shared__ unsigned parent[N];
    __shared__ __align__(16) unsigned pb[2][N];
    __shared__ float deaths[N];
    __shared__ unsigned wsum[16];    // counting-sort wave totals
    __shared__ int deathCount;

    const int t = threadIdx.x;
    const int blk = blockIdx.x;
    const float* __restrict__ src = (blk < 64 ? gts : preds) + (size_t)(blk & 63) * N * 3;

    // ---- stage + init ----
    {
        float* stg = (float*)&spts[0];
        if (t < 768) ((float4*)stg)[t] = ((const float4*)src)[t];
        __syncthreads();
        float x = stg[3 * t], y = stg[3 * t + 1], z = stg[3 * t + 2];
        pts[t] = make_float4(x, y, z, __uint_as_float((unsigned)t));
        comp[t] = (unsigned)t;
        parent[t] = (unsigned)t;
        deaths[t] = 0.0f;
        bestComp[t] = INF64;
    }
    if (t == 0) deathCount = 0;
    __syncthreads();

    const int n = t & (HALF - 1);
    const int h = t >> 9;
    const int n2 = n + HALF;
    const int jbase = h * HALF;
    float4 pA = pts[n], pB = pts[n2];
    const v2f pxv = (v2f){pA.x, pB.x};
    const v2f pyv = (v2f){pA.y, pB.y};
    const v2f pzv = (v2f){pA.z, pB.z};

    // ---- merge phase 1 from bests1 (every node is a root and hooks to its NN) ----
    if (nPre >= 1) {
        unsigned b1 = bests1[(size_t)blk * N + t];
        unsigned j1 = b1 & 0x3FFu;
        unsigned e1 = b1 & 0xFFFFF800u;
        parent[t] = j1;
        __syncthreads();
        {
            unsigned p = j1;
            unsigned gp = parent[p];
            bool mutual = (gp == (unsigned)t);
            bool rec = !mutual || ((unsigned)t < p);
            float dval = rec ? sqrtf(__uint_as_float(e1) + 1e-12f) : 0.0f;
            ull m = __ballot(rec);
            int cnt = __popcll(m);
            int base = 0;
            if ((t & 63) == 0 && cnt) base = atomicAdd(&deathCount, cnt);
            base = __shfl(base, 0, 64);
            if (rec) {
                int idx = base + __popcll(m & ((1ull << (t & 63)) - 1ull));
                if (idx < N - 1) deaths[idx] = dval;
            }
        }
        __syncthreads();
        {
            unsigned r = walk_root(parent, (unsigned)t);
            parent[t] = r;
            comp[t] = r;
            pts[t].w = __uint_as_float(r);
        }
        __syncthreads();
    }

    // ---- merge phase 2 from bests2 ----
    if (nPre >= 2) {
        unsigned b2 = bests2[(size_t)blk * N + t];
        if (b2 != INF32) {
            unsigned j2 = b2 & 0x3FFu, e2 = b2 & 0xFFFFF800u;
            unsigned mn = umin32((unsigned)t, j2), mx = umax32((unsigned)t, j2);
            atomicMin(&bestComp[comp[t]], ((ull)e2 << 20) | (ull)((mn << 10) | mx));
        }
        __syncthreads();
        const unsigned c = (unsigned)t;
        const bool isRoot = (parent[c] == c);
        {
            ull bc = bestComp[c];
            if (isRoot && bc != INF64) {
                unsigned mn = (unsigned)((bc >> 10) & 0x3FFu);
                unsigned mx = (unsigned)(bc & 0x3FFu);
                unsigned cm = comp[mn];
                parent[c] = (cm == c) ? comp[mx] : cm;
            }
        }
        __syncthreads();
        {
            bool rec = false;
            float dval = 0.0f;
            unsigned p = parent[c];
            if (isRoot && p != c) {
                unsigned gp = parent[p];
                bool mutual = (gp == c);
                rec = !mutual || (c < p);
                if (rec) dval = sqrtf(__uint_as_float((unsigned)(bestComp[c] >> 20)) + 1e-12f);
            }
            ull m = __ballot(rec);
            int cnt = __popcll(m);
            int base = 0;
            if ((t & 63) == 0 && cnt) base = atomicAdd(&deathCount, cnt);
            base = __shfl(base, 0, 64);
            if (rec) {
                int idx = base + __popcll(m & ((1ull << (t & 63)) - 1ull));
                if (idx < N - 1) deaths[idx] = dval;
            }
        }
        __syncthreads();
        {
            unsigned r = walk_root(parent, c);
            parent[t] = r;
            unsigned nc = walk_root(parent, comp[t]);
            comp[t] = nc;
            pts[t].w = __uint_as_float(nc);
            bestComp[t] = INF64;
        }
        __syncthreads();
    }

    // ---- in-kernel Boruvka phases (fallback path; never triggers on this data) ----
    int phase = nPre;
    while (N - deathCount > (nPre ? SWITCH : 1) && phase < PHASE_CAP) {
        const unsigned c0 = comp[n], c1 = comp[n2];
        unsigned best0 = INF32, best1 = INF32;
        #pragma unroll 8
        for (int jj = 0; jj < HALF; ++jj) {
            int j = jbase + jj;
            float4 pj = pts[j];
            unsigned cj = __float_as_uint(pj.w);
            v2f dx = pxv - (v2f){pj.x, pj.x};
            v2f dy = pyv - (v2f){pj.y, pj.y};
            v2f dz = pzv - (v2f){pj.z, pj.z};
            v2f e = dx * dx;
            e = __builtin_elementwise_fma(dy, dy, e);
            e = __builtin_elementwise_fma(dz, dz, e);
            unsigned k0 = (__float_as_uint(e.x) & 0xFFFFF800u) | (unsigned)j;
            unsigned k1 = (__float_as_uint(e.y) & 0xFFFFF800u) | (unsigned)j;
            k0 = (cj == c0) ? INF32 : k0;
            k1 = (cj == c1) ? INF32 : k1;
            best0 = umin32(best0, k0);
            best1 = umin32(best1, k1);
        }
        pb[h][n] = best0;
        pb[h][n2] = best1;
        __syncthreads();
        if (h == 0) {
            #pragma unroll
            for (int s = 0; s < 2; ++s) {
                int m = s == 0 ? n : n2;
                unsigned fb = umin32(pb[0][m], pb[1][m]);
                if (fb != INF32) {
                    unsigned j = fb & 0x3FFu, e = fb & 0xFFFFF800u;
                    unsigned mn = umin32((unsigned)m, j), mx = umax32((unsigned)m, j);
                    ull key = ((ull)e << 20) | (ull)((mn << 10) | mx);
                    if (phase == 0) bestComp[m] = key;
                    else atomicMin(&bestComp[comp[m]], key);
                }
            }
        }
        __syncthreads();
        const unsigned c = (unsigned)t;
        const bool isRoot = (parent[c] == c);
        {
            ull bc = bestComp[c];
            if (isRoot && bc != INF64) {
                unsigned mn = (unsigned)((bc >> 10) & 0x3FFu);
                unsigned mx = (unsigned)(bc & 0x3FFu);
                unsigned cm = comp[mn];
                parent[c] = (cm == c) ? comp[mx] : cm;
            }
        }
        __syncthreads();
        {
            bool rec = false;
            float dval = 0.0f;
            unsigned p = parent[c];
            if (isRoot && p != c) {
                unsigned gp = parent[p];
                bool mutual = (gp == c);
                rec = !mutual || (c < p);
                if (rec) dval = sqrtf(__uint_as_float((unsigned)(bestComp[c] >> 20)) + 1e-12f);
            }
            ull m = __ballot(rec);
            int cnt = __popcll(m);
            int base = 0;
            if ((t & 63) == 0 && cnt) base = atomicAdd(&deathCount, cnt);
            base = __shfl(base, 0, 64);
            if (rec) {
                int idx = base + __popcll(m & ((1ull << (t & 63)) - 1ull));
                if (idx < N - 1) deaths[idx] = dval;
            }
        }
        __syncthreads();
        {
            unsigned r = walk_root(parent, c);
            parent[t] = r;
            unsigned nc = walk_root(parent, comp[t]);
            comp[t] = nc;
            pts[t].w = __uint_as_float(nc);
            bestComp[t] = INF64;
        }
        __syncthreads();
        ++phase;
    }

    // ================= Contracted Prim on remaining comps =================
    const int dcbase = deathCount;
    const int comps = N - dcbase;
    if (comps > 1) {
        unsigned* scomp = &pb[0][0];     // comp id per sorted slot
        unsigned* hist = &pb[1][0];      // counts -> running offsets
        unsigned* wavemin = &pb[1][0];   // double-buffered: [(step&1)*8 + wid]
        uint2* segs = (uint2*)&bestComp[0];
        const int lane = t & 63;
        const int wid = t >> 6;

        hist[t] = 0;
        __syncthreads();
        atomicAdd(&hist[comp[t]], 1u);
        __syncthreads();
        unsigned cnt = hist[t];
        unsigned inc = cnt;
        #pragma unroll
        for (int d = 1; d < 64; d <<= 1) {
            unsigned u = __shfl_up(inc, d, 64);
            if (lane >= d) inc += u;
        }
        if (lane == 63) wsum[wid] = inc;
        __syncthreads();
        unsigned wof = 0;
        for (int i = 0; i < wid; ++i) wof += wsum[i];
        unsigned excl = wof + inc - cnt;
        if (cnt) { segs[t].x = excl; segs[t].y = excl + cnt; }
        __syncthreads();
        hist[t] = excl;
        __syncthreads();
        {
            unsigned pos = atomicAdd(&hist[comp[t]], 1u);
            spts[pos] = pts[t];
            scomp[pos] = comp[t];
        }
        __syncthreads();

        unsigned c_cur = comp[0];
        v2f pxv2 = (v2f){0.f, 0.f}, pyv2 = pxv2, pzv2 = pxv2;
        unsigned myc0 = 0, myc1 = 0, md0 = INF32, md1 = INF32;
        if (t < HALF) {
            float4 q0 = spts[t], q1 = spts[t + HALF];
            myc0 = scomp[t];
            myc1 = scomp[t + HALF];
            pxv2 = (v2f){q0.x, q1.x};
            pyv2 = (v2f){q0.y, q1.y};
            pzv2 = (v2f){q0.z, q1.z};
            if (myc0 == c_cur) pxv2.x = INFINITY;
            if (myc1 == c_cur) pxv2.y = INFINITY;
        }

        for (int step = 0; step < comps - 1; ++step) {
            if (t < HALF) {
                uint2 sg = segs[c_cur];
                const int jb = (int)sg.x, je = (int)sg.y, jl = je - 1;
                for (int base = jb; base < je; base += 4) {
                    float4 q0 = spts[base];
                    float4 q1 = spts[imin32(base + 1, jl)];
                    float4 q2 = spts[imin32(base + 2, jl)];
                    float4 q3 = spts[imin32(base + 3, jl)];
                    #define RELAX(qq)                                                        \
                        {                                                                    \
                            v2f dx = pxv2 - (v2f){qq.x, qq.x};                               \
                            v2f dy = pyv2 - (v2f){qq.y, qq.y};                               \
                            v2f dz = pzv2 - (v2f){qq.z, qq.z};                               \
                            v2f e = dx * dx;                                                 \
                            e = __builtin_elementwise_fma(dy, dy, e);                        \
                            e = __builtin_elementwise_fma(dz, dz, e);                        \
                            md0 = umin32(md0, (__float_as_uint(e.x) & 0xFFFFFC00u) | myc0);  \
                            md1 = umin32(md1, (__float_as_uint(e.y) & 0xFFFFFC00u) | myc1);  \
                        }
                    RELAX(q0) RELAX(q1) RELAX(q2) RELAX(q3)
                    #undef RELAX
                }
                unsigned v = umin32(md0, md1);
                DPP_MIN_SHR(v, 1);
                DPP_MIN_SHR(v, 2);
                DPP_MIN_SHR(v, 4);
                DPP_MIN_SHR(v, 8);
                unsigned r0 = (unsigned)__builtin_amdgcn_readlane((int)v, 15);
                unsigned r1 = (unsigned)__builtin_amdgcn_readlane((int)v, 31);
                unsigned r2 = (unsigned)__builtin_amdgcn_readlane((int)v, 47);
                unsigned r3 = (unsigned)__builtin_amdgcn_readlane((int)v, 63);
                if (lane == 0)
                    wavemin[(step & 1) * 8 + wid] = umin32(umin32(r0, r1), umin32(r2, r3));
            }
            __syncthreads();                     // single barrier per step (dbuf-safe)
            if (t < HALF) {
                const uint4* wmv = (const uint4*)(wavemin + (step & 1) * 8);
                uint4 u0 = wmv[0], u1 = wmv[1];
                unsigned m0 = umin32(umin32(u0.x, u0.y), umin32(u0.z, u0.w));
                unsigned m1 = umin32(umin32(u1.x, u1.y), umin32(u1.z, u1.w));
                unsigned G = umin32(m0, m1);
                c_cur = G & 0x3FFu;
                if (t == 0)
                    deaths[dcbase + step] = sqrtf(__uint_as_float(G & 0xFFFFFC00u) + 1e-12f);
                if (myc0 == c_cur) { pxv2.x = INFINITY; md0 = INF32; }
                if (myc1 == c_cur) { pxv2.y = INFINITY; md1 = INF32; }
            }
        }
    }

    // ---- hybrid bitonic sort (register element; j<64 via shfl_xor, j>=64 via LDS) ----
    if (t == 0) deaths[N - 1] = INFINITY;
    __syncthreads();
    {
        float v = deaths[t];
        #pragma unroll
        for (int k = 2; k <= N; k <<= 1) {
            const bool up = ((t & k) == 0);
            #pragma unroll
            for (int j = k >> 1; j > 0; j >>= 1) {
                float u;
                if (j >= 64) {
                    deaths[t] = v;
                    __syncthreads();
                    u = deaths[t ^ j];
                    __syncthreads();
                } else {
                    u = __shfl_xor(v, j, 64);
                }
                v = (((t & j) == 0) == up) ? fminf(v, u) : fmaxf(v, u);
            }
        }
        float* dst = ws + (size_t)blk * N;
        dst[t] = (t < N - 1) ? v : 0.0f;
    }
}

// Fused diff: 64 blocks; per-batch |a-b| sum -> atomicAdd into out (pre-zeroed).
// (r3-proven scheme; r7's single-block variant was one-CU latency-bound, ~+20 us.)
__global__ __launch_bounds__(256) void diff_kernel(const float* __restrict__ ws,
                                                   float* __restrict__ out) {
    __shared__ float red[4];
    const int t = threadIdx.x;
    const int b = blockIdx.x;
    const float* a = ws + (size_t)b * N;
    const float* c = ws + (size_t)(64 + b) * N;
    float sum = 0.0f;
    for (int i = t; i < N; i += 256)
        sum += fabsf(a[i] - c[i]);
    #pragma unroll
    for (int off = 32; off > 0; off >>= 1)
        sum += __shfl_down(sum, off, 64);
    if ((t & 63) == 0) red[t >> 6] = sum;
    __syncthreads();
    if (t == 0)
        atomicAdd(out, (red[0] + red[1] + red[2] + red[3]) * (1.0f / 64.0f));
}

extern "C" void kernel_launch(void* const* d_in, const int* in_sizes, int n_in,
                              void* d_out, int out_size, void* d_ws, size_t ws_size,
                              hipStream_t stream) {
    const float* gts = (const float*)d_in[0];
    const float* preds = (const float*)d_in[1];
    float* ws = (float*)d_ws;                     // sorted deaths live at ws[0 .. 128*N)
    unsigned* bests1 = (unsigned*)d_ws;           // 512 KiB (overwritten by sorted deaths)
    unsigned* bests2 = bests1 + 128 * N;          // 512 KiB
    const bool big = ws_size >= (size_t)(2u * 128u * N * 4u);

    if (big) {
        hipLaunchKernelGGL(scan1_kernel, dim3(256), dim3(T), 0, stream, gts, preds, bests1);
        hipLaunchKernelGGL(scan2_kernel, dim3(256), dim3(T), 0, stream, gts, preds, bests1, bests2);
        hipLaunchKernelGGL(final_kernel, dim3(128), dim3(T), 0, stream,
                           gts, preds, ws, bests1, bests2, 2);
    } else {
        hipLaunchKernelGGL(final_kernel, dim3(128), dim3(T), 0, stream,
                           gts, preds, ws, (const unsigned*)nullptr, (const unsigned*)nullptr, 0);
    }
    hipMemsetAsync(d_out, 0, sizeof(float), stream);   // out accumulated via atomicAdd
    hipLaunchKernelGGL(diff_kernel, dim3(64), dim3(256), 0, stream, ws, (float*)d_out);
}

// Round 9
// 213.476 us; speedup vs baseline: 2.4307x; 1.0221x over previous
//
#include <hip/hip_runtime.h>
#include <math.h>

#define N 1024
#define T 1024           // scan blocks: 16 waves
#define TF 512           // final block: 8 waves, 2 elements/thread (barrier cost halved)
#define HALF 512
#define PHASE_CAP 10
#define SWITCH 80        // in-block Boruvka only if comps > 80 (measured: never on this data)

typedef float v2f __attribute__((ext_vector_type(2)));
typedef unsigned long long ull;

#define INF64 0xFFFFFFFFFFFFFFFFull
#define INF32 0xFFFFFFFFu

__device__ __forceinline__ unsigned umin32(unsigned a, unsigned b) { return a < b ? a : b; }
__device__ __forceinline__ unsigned umax32(unsigned a, unsigned b) { return a > b ? a : b; }
__device__ __forceinline__ int imin32(int a, int b) { return a < b ? a : b; }

// Root walk with 2-cycle detection (keys globally distinct => cycles are exactly
// mutual pairs; root = min of the pair). Safe under concurrent parent[x] <- root(x).
__device__ __forceinline__ unsigned walk_root(const unsigned* parent, unsigned x) {
    unsigned prev = x, cur = parent[x];
    while (cur != prev) {
        unsigned nxt = parent[cur];
        if (nxt == prev) { cur = umin32(cur, prev); break; }
        prev = cur; cur = nxt;
    }
    return cur;
}

// DPP row_shr min step (row = 16 lanes), identity = 0xFFFFFFFF
#define DPP_MIN_SHR(v, sh)                                                                   \
    do {                                                                                     \
        unsigned _t = (unsigned)__builtin_amdgcn_update_dpp(                                 \
            (int)0xFFFFFFFF, (int)(v), 0x110 | (sh), 0xF, 0xF, false);                       \
        (v) = umin32((v), _t);                                                               \
    } while (0)

// ---------- phase-1 scan: 256 blocks = (cloud, node-half). r8-exact. ----------
__global__ __launch_bounds__(T) void scan1_kernel(const float* __restrict__ gts,
                                                  const float* __restrict__ preds,
                                                  unsigned* __restrict__ bests1) {
    __shared__ float4 p4[N];
    __shared__ unsigned pb8[8][HALF];
    const int t = threadIdx.x;
    const int cloud = blockIdx.x >> 1;
    const int nh = blockIdx.x & 1;
    const float* __restrict__ src = (cloud < 64 ? gts : preds) + (size_t)(cloud & 63) * N * 3;

    {
        float* stg = (float*)&pb8[0][0];
        if (t < 768) ((float4*)stg)[t] = ((const float4*)src)[t];
        __syncthreads();
        p4[t] = make_float4(stg[3 * t], stg[3 * t + 1], stg[3 * t + 2], 0.0f);
        __syncthreads();
    }

    const int q = t & 127;
    const int s = t >> 7;
    const int jbase = s << 7;
    const int n0 = nh * HALF + q;
    const int n1 = n0 + 128, n2 = n0 + 256, n3 = n0 + 384;
    const float4 a0 = p4[n0], a1 = p4[n1], a2 = p4[n2], a3 = p4[n3];
    const v2f axA = (v2f){a0.x, a1.x}, ayA = (v2f){a0.y, a1.y}, azA = (v2f){a0.z, a1.z};
    const v2f axB = (v2f){a2.x, a3.x}, ayB = (v2f){a2.y, a3.y}, azB = (v2f){a2.z, a3.z};
    unsigned b0 = INF32, b1 = INF32, b2 = INF32, b3 = INF32;
    #pragma unroll 4
    for (int jj = 0; jj < 128; jj += 2) {
        const int j = jbase + jj;
        const float4 qa = p4[j];
        const float4 qb = p4[j + 1];
        #define STEP1(QQ, JV)                                                           \
        {                                                                               \
            const v2f sxv = (v2f){QQ.x, QQ.x}, syv = (v2f){QQ.y, QQ.y},                 \
                      szv = (v2f){QQ.z, QQ.z};                                          \
            v2f dxA = axA - sxv, dyA = ayA - syv, dzA = azA - szv;                      \
            v2f eA = dxA * dxA;                                                         \
            eA = __builtin_elementwise_fma(dyA, dyA, eA);                               \
            eA = __builtin_elementwise_fma(dzA, dzA, eA);                               \
            v2f dxB = axB - sxv, dyB = ayB - syv, dzB = azB - szv;                      \
            v2f eB = dxB * dxB;                                                         \
            eB = __builtin_elementwise_fma(dyB, dyB, eB);                               \
            eB = __builtin_elementwise_fma(dzB, dzB, eB);                               \
            unsigned kk;                                                                \
            kk = (__float_as_uint(eA.x) & 0xFFFFF800u) | (unsigned)(JV);                \
            b0 = umin32(b0, ((JV) == n0) ? INF32 : kk);                                 \
            kk = (__float_as_uint(eA.y) & 0xFFFFF800u) | (unsigned)(JV);                \
            b1 = umin32(b1, ((JV) == n1) ? INF32 : kk);                                 \
            kk = (__float_as_uint(eB.x) & 0xFFFFF800u) | (unsigned)(JV);                \
            b2 = umin32(b2, ((JV) == n2) ? INF32 : kk);                                 \
            kk = (__float_as_uint(eB.y) & 0xFFFFF800u) | (unsigned)(JV);                \
            b3 = umin32(b3, ((JV) == n3) ? INF32 : kk);                                 \
        }
        STEP1(qa, j)
        STEP1(qb, j + 1)
        #undef STEP1
    }
    pb8[s][q] = b0; pb8[s][q + 128] = b1; pb8[s][q + 256] = b2; pb8[s][q + 384] = b3;
    __syncthreads();
    if (t < HALF) {
        unsigned best = umin32(umin32(pb8[0][t], pb8[1][t]), umin32(pb8[2][t], pb8[3][t]));
        best = umin32(best, umin32(umin32(pb8[4][t], pb8[5][t]), umin32(pb8[6][t], pb8[7][t])));
        bests1[(size_t)cloud * N + nh * HALF + t] = best;
    }
}

// ---------- phase-2 scan: r8-exact ----------
__global__ __launch_bounds__(T) void scan2_kernel(const float* __restrict__ gts,
                                                  const float* __restrict__ preds,
                                                  const unsigned* __restrict__ bests1,
                                                  unsigned* __restrict__ bests2) {
    __shared__ float4 p4[N];
    __shared__ unsigned cw[N];
    __shared__ unsigned parent[N];
    __shared__ unsigned pb8[8][HALF];
    const int t = threadIdx.x;
    const int cloud = blockIdx.x >> 1;
    const int nh = blockIdx.x & 1;
    const float* __restrict__ src = (cloud < 64 ? gts : preds) + (size_t)(cloud & 63) * N * 3;

    {
        float* stg = (float*)&pb8[0][0];
        if (t < 768) ((float4*)stg)[t] = ((const float4*)src)[t];
        __syncthreads();
        p4[t] = make_float4(stg[3 * t], stg[3 * t + 1], stg[3 * t + 2], 0.0f);
    }
    parent[t] = bests1[(size_t)cloud * N + t] & 0x3FFu;
    __syncthreads();
    {
        unsigned r = walk_root(parent, (unsigned)t);
        parent[t] = r;
        cw[t] = r;
    }
    __syncthreads();

    const int q = t & 127;
    const int s = t >> 7;
    const int jbase = s << 7;
    const int n0 = nh * HALF + q;
    const int n1 = n0 + 128, n2 = n0 + 256, n3 = n0 + 384;
    const unsigned c0 = cw[n0], c1 = cw[n1], c2 = cw[n2], c3 = cw[n3];
    const float4 a0 = p4[n0], a1 = p4[n1], a2 = p4[n2], a3 = p4[n3];
    const v2f axA = (v2f){a0.x, a1.x}, ayA = (v2f){a0.y, a1.y}, azA = (v2f){a0.z, a1.z};
    const v2f axB = (v2f){a2.x, a3.x}, ayB = (v2f){a2.y, a3.y}, azB = (v2f){a2.z, a3.z};
    unsigned b0 = INF32, b1 = INF32, b2 = INF32, b3 = INF32;
    #pragma unroll 4
    for (int jj = 0; jj < 128; jj += 2) {
        const int j = jbase + jj;
        const float4 qa = p4[j];
        const float4 qb = p4[j + 1];
        uint2 cj = *(const uint2*)&cw[j];
        #define STEP2(QQ, CJ, JV)                                                       \
        {                                                                               \
            const v2f sxv = (v2f){QQ.x, QQ.x}, syv = (v2f){QQ.y, QQ.y},                 \
                      szv = (v2f){QQ.z, QQ.z};                                          \
            v2f dxA = axA - sxv, dyA = ayA - syv, dzA = azA - szv;                      \
            v2f eA = dxA * dxA;                                                         \
            eA = __builtin_elementwise_fma(dyA, dyA, eA);                               \
            eA = __builtin_elementwise_fma(dzA, dzA, eA);                               \
            v2f dxB = axB - sxv, dyB = ayB - syv, dzB = azB - szv;                      \
            v2f eB = dxB * dxB;                                                         \
            eB = __builtin_elementwise_fma(dyB, dyB, eB);                               \
            eB = __builtin_elementwise_fma(dzB, dzB, eB);                               \
            unsigned kk;                                                                \
            kk = (__float_as_uint(eA.x) & 0xFFFFF800u) | (unsigned)(JV);                \
            b0 = umin32(b0, ((CJ) == c0) ? INF32 : kk);                                 \
            kk = (__float_as_uint(eA.y) & 0xFFFFF800u) | (unsigned)(JV);                \
            b1 = umin32(b1, ((CJ) == c1) ? INF32 : kk);                                 \
            kk = (__float_as_uint(eB.x) & 0xFFFFF800u) | (unsigned)(JV);                \
            b2 = umin32(b2, ((CJ) == c2) ? INF32 : kk);                                 \
            kk = (__float_as_uint(eB.y) & 0xFFFFF800u) | (unsigned)(JV);                \
            b3 = umin32(b3, ((CJ) == c3) ? INF32 : kk);                                 \
        }
        STEP2(qa, cj.x, j)
        STEP2(qb, cj.y, j + 1)
        #undef STEP2
    }
    pb8[s][q] = b0; pb8[s][q + 128] = b1; pb8[s][q + 256] = b2; pb8[s][q + 384] = b3;
    __syncthreads();
    if (t < HALF) {
        unsigned best = umin32(umin32(pb8[0][t], pb8[1][t]), umin32(pb8[2][t], pb8[3][t]));
        best = umin32(best, umin32(umin32(pb8[4][t], pb8[5][t]), umin32(pb8[6][t], pb8[7][t])));
        bests2[(size_t)cloud * N + nh * HALF + t] = best;
    }
}

// ---------- final: 512 threads, 2 elements/thread (e0=t, e1=t+512) ----------
// Deaths multiset identical to the 1024-thread version (only compaction order
// differs; deaths are sorted before use) -> bit-identical output.
__global__ __launch_bounds__(TF) void final_kernel(const float* __restrict__ gts,
                                                   const float* __restrict__ preds,
                                                   float* __restrict__ ws,
                                                   const unsigned* __restrict__ bests1,
                                                   const unsigned* __restrict__ bests2,
                                                   int nPre) {
    __shared__ float4 pts[N];
    __shared__ float4 spts[N];
    __shared__ unsigned comp[N];
    __shared__ ull bestComp[N];
    __shared__ unsigned parent[N];
    __shared__ __align__(16) unsigned pb[2][N];
    __shared__ float deaths[N];
    __shared__ unsigned wsum[16];
    __shared__ int deathCount;

    const int t = threadIdx.x;
    const int tb = t + HALF;             // second element
    const int blk = blockIdx.x;
    const float* __restrict__ src = (blk < 64 ? gts : preds) + (size_t)(blk & 63) * N * 3;

    // ---- stage + init ----
    {
        float* stg = (float*)&spts[0];
        for (int i = t; i < 768; i += TF) ((float4*)stg)[i] = ((const float4*)src)[i];
        __syncthreads();
        #pragma unroll
        for (int e = t; e < N; e += TF) {
            float x = stg[3 * e], y = stg[3 * e + 1], z = stg[3 * e + 2];
            pts[e] = make_float4(x, y, z, __uint_as_float((unsigned)e));
            comp[e] = (unsigned)e;
            parent[e] = (unsigned)e;
            deaths[e] = 0.0f;
            bestComp[e] = INF64;
        }
    }
    if (t == 0) deathCount = 0;
    __syncthreads();

    // ---- merge phase 1 from bests1 ----
    if (nPre >= 1) {
        unsigned bA = bests1[(size_t)blk * N + t];
        unsigned bB = bests1[(size_t)blk * N + tb];
        unsigned jA = bA & 0x3FFu, eAb = bA & 0xFFFFF800u;
        unsigned jB = bB & 0x3FFu, eBb = bB & 0xFFFFF800u;
        parent[t] = jA;
        parent[tb] = jB;
        __syncthreads();
        {
            unsigned gpA = parent[jA];
            bool recA = !(gpA == (unsigned)t) || ((unsigned)t < jA);
            float dvalA = recA ? sqrtf(__uint_as_float(eAb) + 1e-12f) : 0.0f;
            unsigned gpB = parent[jB];
            bool recB = !(gpB == (unsigned)tb) || ((unsigned)tb < jB);
            float dvalB = recB ? sqrtf(__uint_as_float(eBb) + 1e-12f) : 0.0f;
            ull mA = __ballot(recA), mB = __ballot(recB);
            int cntA = __popcll(mA);
            int cnt = cntA + __popcll(mB);
            int base = 0;
            if ((t & 63) == 0 && cnt) base = atomicAdd(&deathCount, cnt);
            base = __shfl(base, 0, 64);
            ull below = (1ull << (t & 63)) - 1ull;
            if (recA) { int idx = base + __popcll(mA & below); if (idx < N - 1) deaths[idx] = dvalA; }
            if (recB) { int idx = base + cntA + __popcll(mB & below); if (idx < N - 1) deaths[idx] = dvalB; }
        }
        __syncthreads();
        {
            unsigned r = walk_root(parent, (unsigned)t);
            parent[t] = r; comp[t] = r; pts[t].w = __uint_as_float(r);
            unsigned r2 = walk_root(parent, (unsigned)tb);
            parent[tb] = r2; comp[tb] = r2; pts[tb].w = __uint_as_float(r2);
        }
        __syncthreads();
    }

    // ---- merge phase 2 from bests2 ----
    if (nPre >= 2) {
        {
            unsigned b2 = bests2[(size_t)blk * N + t];
            if (b2 != INF32) {
                unsigned j2 = b2 & 0x3FFu, e2 = b2 & 0xFFFFF800u;
                unsigned mn = umin32((unsigned)t, j2), mx = umax32((unsigned)t, j2);
                atomicMin(&bestComp[comp[t]], ((ull)e2 << 20) | (ull)((mn << 10) | mx));
            }
            b2 = bests2[(size_t)blk * N + tb];
            if (b2 != INF32) {
                unsigned j2 = b2 & 0x3FFu, e2 = b2 & 0xFFFFF800u;
                unsigned mn = umin32((unsigned)tb, j2), mx = umax32((unsigned)tb, j2);
                atomicMin(&bestComp[comp[tb]], ((ull)e2 << 20) | (ull)((mn << 10) | mx));
            }
        }
        __syncthreads();
        const bool isRootA = (parent[t] == (unsigned)t);
        const bool isRootB = (parent[tb] == (unsigned)tb);
        {
            ull bc = bestComp[t];
            if (isRootA && bc != INF64) {
                unsigned mn = (unsigned)((bc >> 10) & 0x3FFu), mx = (unsigned)(bc & 0x3FFu);
                unsigned cm = comp[mn];
                parent[t] = (cm == (unsigned)t) ? comp[mx] : cm;
            }
            bc = bestComp[tb];
            if (isRootB && bc != INF64) {
                unsigned mn = (unsigned)((bc >> 10) & 0x3FFu), mx = (unsigned)(bc & 0x3FFu);
                unsigned cm = comp[mn];
                parent[tb] = (cm == (unsigned)tb) ? comp[mx] : cm;
            }
        }
        __syncthreads();
        {
            bool recA = false, recB = false;
            float dvalA = 0.0f, dvalB = 0.0f;
            unsigned p = parent[t];
            if (isRootA && p != (unsigned)t) {
                unsigned gp = parent[p];
                recA = !(gp == (unsigned)t) || ((unsigned)t < p);
                if (recA) dvalA = sqrtf(__uint_as_float((unsigned)(bestComp[t] >> 20)) + 1e-12f);
            }
            p = parent[tb];
            if (isRootB && p != (unsigned)tb) {
                unsigned gp = parent[p];
                recB = !(gp == (unsigned)tb) || ((unsigned)tb < p);
                if (recB) dvalB = sqrtf(__uint_as_float((unsigned)(bestComp[tb] >> 20)) + 1e-12f);
            }
            ull mA = __ballot(recA), mB = __ballot(recB);
            int cntA = __popcll(mA);
            int cnt = cntA + __popcll(mB);
            int base = 0;
            if ((t & 63) == 0 && cnt) base = atomicAdd(&deathCount, cnt);
            base = __shfl(base, 0, 64);
            ull below = (1ull << (t & 63)) - 1ull;
            if (recA) { int idx = base + __popcll(mA & below); if (idx < N - 1) deaths[idx] = dvalA; }
            if (recB) { int idx = base + cntA + __popcll(mB & below); if (idx < N - 1) deaths[idx] = dvalB; }
        }
        __syncthreads();
        {
            unsigned r = walk_root(parent, (unsigned)t);
            parent[t] = r;
            unsigned nc = walk_root(parent, comp[t]);
            comp[t] = nc; pts[t].w = __uint_as_float(nc); bestComp[t] = INF64;
            r = walk_root(parent, (unsigned)tb);
            parent[tb] = r;
            nc = walk_root(parent, comp[tb]);
            comp[tb] = nc; pts[tb].w = __uint_as_float(nc); bestComp[tb] = INF64;
        }
        __syncthreads();
    }

    // ---- in-block Boruvka phases (fallback; full path when nPre==0) ----
    {
        float4 pA = pts[t], pB = pts[tb];
        const v2f pxv = (v2f){pA.x, pB.x};
        const v2f pyv = (v2f){pA.y, pB.y};
        const v2f pzv = (v2f){pA.z, pB.z};
        int phase = nPre;
        while (N - deathCount > (nPre ? SWITCH : 1) && phase < PHASE_CAP) {
            const unsigned c0 = comp[t], c1 = comp[tb];
            unsigned best0 = INF32, best1 = INF32;
            #pragma unroll 8
            for (int j = 0; j < N; ++j) {
                float4 pj = pts[j];
                unsigned cj = __float_as_uint(pj.w);
                v2f dx = pxv - (v2f){pj.x, pj.x};
                v2f dy = pyv - (v2f){pj.y, pj.y};
                v2f dz = pzv - (v2f){pj.z, pj.z};
                v2f e = dx * dx;
                e = __builtin_elementwise_fma(dy, dy, e);
                e = __builtin_elementwise_fma(dz, dz, e);
                unsigned k0 = (__float_as_uint(e.x) & 0xFFFFF800u) | (unsigned)j;
                unsigned k1 = (__float_as_uint(e.y) & 0xFFFFF800u) | (unsigned)j;
                k0 = (cj == c0) ? INF32 : k0;
                k1 = (cj == c1) ? INF32 : k1;
                best0 = umin32(best0, k0);
                best1 = umin32(best1, k1);
            }
            if (best0 != INF32) {
                unsigned j = best0 & 0x3FFu, e = best0 & 0xFFFFF800u;
                unsigned mn = umin32((unsigned)t, j), mx = umax32((unsigned)t, j);
                ull key = ((ull)e << 20) | (ull)((mn << 10) | mx);
                if (phase == 0) bestComp[t] = key;
                else atomicMin(&bestComp[comp[t]], key);
            }
            if (best1 != INF32) {
                unsigned j = best1 & 0x3FFu, e = best1 & 0xFFFFF800u;
                unsigned mn = umin32((unsigned)tb, j), mx = umax32((unsigned)tb, j);
                ull key = ((ull)e << 20) | (ull)((mn << 10) | mx);
                if (phase == 0) bestComp[tb] = key;
                else atomicMin(&bestComp[comp[tb]], key);
            }
            __syncthreads();
            const bool isRootA = (parent[t] == (unsigned)t);
            const bool isRootB = (parent[tb] == (unsigned)tb);
            {
                ull bc = bestComp[t];
                if (isRootA && bc != INF64) {
                    unsigned mn = (unsigned)((bc >> 10) & 0x3FFu), mx = (unsigned)(bc & 0x3FFu);
                    unsigned cm = comp[mn];
                    parent[t] = (cm == (unsigned)t) ? comp[mx] : cm;
                }
                bc = bestComp[tb];
                if (isRootB && bc != INF64) {
                    unsigned mn = (unsigned)((bc >> 10) & 0x3FFu), mx = (unsigned)(bc & 0x3FFu);
                    unsigned cm = comp[mn];
                    parent[tb] = (cm == (unsigned)tb) ? comp[mx] : cm;
                }
            }
            __syncthreads();
            {
                bool recA = false, recB = false;
                float dvalA = 0.0f, dvalB = 0.0f;
                unsigned p = parent[t];
                if (isRootA && p != (unsigned)t) {
                    unsigned gp = parent[p];
                    recA = !(gp == (unsigned)t) || ((unsigned)t < p);
                    if (recA) dvalA = sqrtf(__uint_as_float((unsigned)(bestComp[t] >> 20)) + 1e-12f);
                }
                p = parent[tb];
                if (isRootB && p != (unsigned)tb) {
                    unsigned gp = parent[p];
                    recB = !(gp == (unsigned)tb) || ((unsigned)tb < p);
                    if (recB) dvalB = sqrtf(__uint_as_float((unsigned)(bestComp[tb] >> 20)) + 1e-12f);
                }
                ull mA = __ballot(recA), mB = __ballot(recB);
                int cntA = __popcll(mA);
                int cnt = cntA + __popcll(mB);
                int base = 0;
                if ((t & 63) == 0 && cnt) base = atomicAdd(&deathCount, cnt);
                base = __shfl(base, 0, 64);
                ull below = (1ull << (t & 63)) - 1ull;
                if (recA) { int idx = base + __popcll(mA & below); if (idx < N - 1) deaths[idx] = dvalA; }
                if (recB) { int idx = base + cntA + __popcll(mB & below); if (idx < N - 1) deaths[idx] = dvalB; }
            }
            __syncthreads();
            {
                unsigned r = walk_root(parent, (unsigned)t);
                parent[t] = r;
                unsigned nc = walk_root(parent, comp[t]);
                comp[t] = nc; pts[t].w = __uint_as_float(nc); bestComp[t] = INF64;
                r = walk_root(parent, (unsigned)tb);
                parent[tb] = r;
                nc = walk_root(parent, comp[tb]);
                comp[tb] = nc; pts[tb].w = __uint_as_float(nc); bestComp[tb] = INF64;
            }
            __syncthreads();
            ++phase;
        }
    }

    // ================= Contracted Prim on remaining comps =================
    const int dcbase = deathCount;
    const int comps = N - dcbase;
    if (comps > 1) {
        unsigned* scomp = &pb[0][0];
        unsigned* hist = &pb[1][0];
        unsigned* wavemin = &pb[1][0];
        uint2* segs = (uint2*)&bestComp[0];
        const int lane = t & 63;
        const int wid = t >> 6;          // 0..7

        hist[t] = 0; hist[tb] = 0;
        __syncthreads();
        atomicAdd(&hist[comp[t]], 1u);
        atomicAdd(&hist[comp[tb]], 1u);
        __syncthreads();
        unsigned cA = hist[t], cB = hist[tb];
        unsigned incA = cA, incB = cB;
        #pragma unroll
        for (int d = 1; d < 64; d <<= 1) {
            unsigned uA = __shfl_up(incA, d, 64);
            unsigned uB = __shfl_up(incB, d, 64);
            if (lane >= d) { incA += uA; incB += uB; }
        }
        if (lane == 63) { wsum[wid] = incA; wsum[8 + wid] = incB; }
        __syncthreads();
        unsigned wofA = 0, totA = 0, wofB = 0;
        for (int i = 0; i < 8; ++i) {
            unsigned w = wsum[i];
            if (i < wid) wofA += w;
            totA += w;
        }
        for (int i = 0; i < wid; ++i) wofB += wsum[8 + i];
        unsigned exclA = wofA + incA - cA;               // bins 0..511
        unsigned exclB = totA + wofB + incB - cB;        // bins 512..1023
        if (cA) { segs[t].x = exclA; segs[t].y = exclA + cA; }
        if (cB) { segs[tb].x = exclB; segs[tb].y = exclB + cB; }
        __syncthreads();
        hist[t] = exclA; hist[tb] = exclB;
        __syncthreads();
        {
            unsigned pos = atomicAdd(&hist[comp[t]], 1u);
            spts[pos] = pts[t]; scomp[pos] = comp[t];
            pos = atomicAdd(&hist[comp[tb]], 1u);
            spts[pos] = pts[tb]; scomp[pos] = comp[tb];
        }
        __syncthreads();

        unsigned c_cur = comp[0];
        v2f pxv2 = (v2f){0.f, 0.f}, pyv2 = pxv2, pzv2 = pxv2;
        unsigned myc0 = 0, myc1 = 0, md0 = INF32, md1 = INF32;
        {
            float4 q0 = spts[t], q1 = spts[tb];
            myc0 = scomp[t];
            myc1 = scomp[tb];
            pxv2 = (v2f){q0.x, q1.x};
            pyv2 = (v2f){q0.y, q1.y};
            pzv2 = (v2f){q0.z, q1.z};
            if (myc0 == c_cur) pxv2.x = INFINITY;
            if (myc1 == c_cur) pxv2.y = INFINITY;
        }

        for (int step = 0; step < comps - 1; ++step) {
            {
                uint2 sg = segs[c_cur];
                const int jb = (int)sg.x, je = (int)sg.y, jl = je - 1;
                for (int base = jb; base < je; base += 4) {
                    float4 q0 = spts[base];
                    float4 q1 = spts[imin32(base + 1, jl)];
                    float4 q2 = spts[imin32(base + 2, jl)];
                    float4 q3 = spts[imin32(base + 3, jl)];
                    #define RELAX(qq)                                                        \
                        {                                                                    \
                            v2f dx = pxv2 - (v2f){qq.x, qq.x};                               \
                            v2f dy = pyv2 - (v2f){qq.y, qq.y};                               \
                            v2f dz = pzv2 - (v2f){qq.z, qq.z};                               \
                            v2f e = dx * dx;                                                 \
                            e = __builtin_elementwise_fma(dy, dy, e);                        \
                            e = __builtin_elementwise_fma(dz, dz, e);                        \
                            md0 = umin32(md0, (__float_as_uint(e.x) & 0xFFFFFC00u) | myc0);  \
                            md1 = umin32(md1, (__float_as_uint(e.y) & 0xFFFFFC00u) | myc1);  \
                        }
                    RELAX(q0) RELAX(q1) RELAX(q2) RELAX(q3)
                    #undef RELAX
                }
                unsigned v = umin32(md0, md1);
                DPP_MIN_SHR(v, 1);
                DPP_MIN_SHR(v, 2);
                DPP_MIN_SHR(v, 4);
                DPP_MIN_SHR(v, 8);
                unsigned r0 = (unsigned)__builtin_amdgcn_readlane((int)v, 15);
                unsigned r1 = (unsigned)__builtin_amdgcn_readlane((int)v, 31);
                unsigned r2 = (unsigned)__builtin_amdgcn_readlane((int)v, 47);
                unsigned r3 = (unsigned)__builtin_amdgcn_readlane((int)v, 63);
                if (lane == 0)
                    wavemin[(step & 1) * 8 + wid] = umin32(umin32(r0, r1), umin32(r2, r3));
            }
            __syncthreads();                     // 8-wave barrier (was 16)
            {
                const uint4* wmv = (const uint4*)(wavemin + (step & 1) * 8);
                uint4 u0 = wmv[0], u1 = wmv[1];
                unsigned m0 = umin32(umin32(u0.x, u0.y), umin32(u0.z, u0.w));
                unsigned m1 = umin32(umin32(u1.x, u1.y), umin32(u1.z, u1.w));
                unsigned G = umin32(m0, m1);
                c_cur = G & 0x3FFu;
                if (t == 0)
                    deaths[dcbase + step] = sqrtf(__uint_as_float(G & 0xFFFFFC00u) + 1e-12f);
                if (myc0 == c_cur) { pxv2.x = INFINITY; md0 = INF32; }
                if (myc1 == c_cur) { pxv2.y = INFINITY; md1 = INF32; }
            }
        }
    }

    // ---- hybrid bitonic sort, 2 register elements/thread ----
    // j<64: shfl_xor; 64<=j<512: LDS (2 barriers); j==512: in-thread swap.
    {
        float v0 = deaths[t], v1 = deaths[tb];
        if (t == TF - 1) v1 = INFINITY;          // element N-1 pad
        #pragma unroll
        for (int k = 2; k <= N; k <<= 1) {
            #pragma unroll
            for (int j = k >> 1; j > 0; j >>= 1) {
                const bool up0 = ((t & k) == 0);
                const bool up1 = ((tb & k) == 0);
                float u0, u1;
                if (j == 512) {
                    u0 = v1; u1 = v0;
                } else if (j >= 64) {
                    deaths[t] = v0; deaths[tb] = v1;
                    __syncthreads();
                    u0 = deaths[t ^ j];
                    u1 = deaths[tb ^ j];
                    __syncthreads();
                } else {
                    u0 = __shfl_xor(v0, j, 64);
                    u1 = __shfl_xor(v1, j, 64);
                }
                v0 = (((t & j) == 0) == up0) ? fminf(v0, u0) : fmaxf(v0, u0);
                v1 = (((tb & j) == 0) == up1) ? fminf(v1, u1) : fmaxf(v1, u1);
            }
        }
        float* dst = ws + (size_t)blk * N;
        dst[t] = v0;
        dst[tb] = (tb < N - 1) ? v1 : 0.0f;
    }
}

// Fused diff: 64 blocks; per-batch |a-b| sum -> atomicAdd into out (pre-zeroed).
__global__ __launch_bounds__(256) void diff_kernel(const float* __restrict__ ws,
                                                   float* __restrict__ out) {
    __shared__ float red[4];
    const int t = threadIdx.x;
    const int b = blockIdx.x;
    const float* a = ws + (size_t)b * N;
    const float* c = ws + (size_t)(64 + b) * N;
    float sum = 0.0f;
    for (int i = t; i < N; i += 256)
        sum += fabsf(a[i] - c[i]);
    #pragma unroll
    for (int off = 32; off > 0; off >>= 1)
        sum += __shfl_down(sum, off, 64);
    if ((t & 63) == 0) red[t >> 6] = sum;
    __syncthreads();
    if (t == 0)
        atomicAdd(out, (red[0] + red[1] + red[2] + red[3]) * (1.0f / 64.0f));
}

extern "C" void kernel_launch(void* const* d_in, const int* in_sizes, int n_in,
                              void* d_out, int out_size, void* d_ws, size_t ws_size,
                              hipStream_t stream) {
    const float* gts = (const float*)d_in[0];
    const float* preds = (const float*)d_in[1];
    float* ws = (float*)d_ws;                     // sorted deaths live at ws[0 .. 128*N)
    unsigned* bests1 = (unsigned*)d_ws;           // 512 KiB (overwritten by sorted deaths)
    unsigned* bests2 = bests1 + 128 * N;          // 512 KiB
    const bool big = ws_size >= (size_t)(2u * 128u * N * 4u);

    if (big) {
        hipLaunchKernelGGL(scan1_kernel, dim3(256), dim3(T), 0, stream, gts, preds, bests1);
        hipLaunchKernelGGL(scan2_kernel, dim3(256), dim3(T), 0, stream, gts, preds, bests1, bests2);
        hipLaunchKernelGGL(final_kernel, dim3(128), dim3(TF), 0, stream,
                           gts, preds, ws, bests1, bests2, 2);
    } else {
        hipLaunchKernelGGL(final_kernel, dim3(128), dim3(TF), 0, stream,
                           gts, preds, ws, (const unsigned*)nullptr, (const unsigned*)nullptr, 0);
    }
    hipMemsetAsync(d_out, 0, sizeof(float), stream);   // out accumulated via atomicAdd
    hipLaunchKernelGGL(diff_kernel, dim3(64), dim3(256), 0, stream, ws, (float*)d_out);
}